// Round 14
// baseline (287.329 us; speedup 1.0000x reference)
//
#include <hip/hip_runtime.h>
#include <hip/hip_bf16.h>
#include <math.h>

#define NN 10000
#define EE 128000
#define AA 5
#define DD 300
#define HH 8
#define CC 64
#define HC 512
#define MM (AA*NN)   // 50000 rows total
#define KP 320       // K padded to multiple of 32
#define NT (KP / 32) // 10 K-steps
#define NBM ((MM + 63) / 64)   // 782 row-tiles
#define SCB 40       // scan: blocks per answer
#define SCN 250      // scan: nodes per block  (SCB*SCN == NN)

typedef __attribute__((ext_vector_type(8))) _Float16 f16x8;
typedef __attribute__((ext_vector_type(4))) float f32x4;
typedef __attribute__((ext_vector_type(2))) float f32x2;
typedef unsigned short ushort;
typedef unsigned char uchar;

__device__ __forceinline__ ushort f2bf(float f) {
    unsigned u = __float_as_uint(f);
    unsigned r = u + 0x7fffu + ((u >> 16) & 1u);   // RN-even
    return (ushort)(r >> 16);
}
__device__ __forceinline__ float bf2f(ushort h) {
    return __uint_as_float(((unsigned)h) << 16);
}
__device__ __forceinline__ float leaky_exp(float v) {
    v = v > 0.f ? v : 0.2f * v;
    return __expf(v);
}

// ---------------- CSR build ----------------

__global__ void count_edges(const int* __restrict__ ei, int* __restrict__ cnt) {
    int a = blockIdx.y;
    int e = blockIdx.x * 256 + threadIdx.x;
    if (e < EE) {
        int dst = ei[(size_t)a * 2 * EE + EE + e];
        atomicAdd(&cnt[a * NN + dst], 1);
    }
}

// --- hierarchical exclusive scan of cnt -> offs, cursor (3 small kernels) ---

__global__ __launch_bounds__(256) void scan_bsum(const int* __restrict__ cnt,
                                                 int* __restrict__ bsum) {
    int a = blockIdx.y, b = blockIdx.x;
    int l = threadIdx.x;
    int v = (l < SCN) ? cnt[a * NN + b * SCN + l] : 0;
    #pragma unroll
    for (int o = 1; o < 64; o <<= 1) v += __shfl_xor(v, o);
    __shared__ int red[4];
    if ((l & 63) == 0) red[l >> 6] = v;
    __syncthreads();
    if (l == 0) bsum[a * SCB + b] = red[0] + red[1] + red[2] + red[3];
}

__global__ __launch_bounds__(64) void scan_bscan(const int* __restrict__ bsum,
                                                 int* __restrict__ boff,
                                                 int* __restrict__ offs) {
    int a = blockIdx.x;
    int l = threadIdx.x;
    int v = (l < SCB) ? bsum[a * SCB + l] : 0;
    int sc = v;
    #pragma unroll
    for (int o = 1; o < 64; o <<= 1) {
        int u = __shfl_up(sc, o);
        if (l >= o) sc += u;
    }
    if (l < SCB) boff[a * SCB + l] = sc - v;
    if (l == 63) offs[a * (NN + 1) + NN] = sc;   // grand total
}

__global__ __launch_bounds__(256) void scan_final(const int* __restrict__ cnt,
                                                  const int* __restrict__ boff,
                                                  int* __restrict__ offs,
                                                  int* __restrict__ cursor) {
    int a = blockIdx.y, b = blockIdx.x;
    int l = threadIdx.x;
    int i = b * SCN + l;
    int v = (l < SCN) ? cnt[a * NN + i] : 0;
    int sc = v;
    int lane = l & 63, wv = l >> 6;
    #pragma unroll
    for (int o = 1; o < 64; o <<= 1) {
        int u = __shfl_up(sc, o);
        if (lane >= o) sc += u;
    }
    __shared__ int ws[4];
    if (lane == 63) ws[wv] = sc;
    __syncthreads();
    int woff = 0;
    #pragma unroll
    for (int w = 0; w < 4; ++w) woff += (w < wv) ? ws[w] : 0;
    if (l < SCN) {
        int o = boff[a * SCB + b] + woff + sc - v;
        offs[a * (NN + 1) + i] = o;
        cursor[a * (NN + 1) + i] = o;
    }
}

__global__ void scatter_edges(const int* __restrict__ ei, int* __restrict__ cursor,
                              int* __restrict__ csr_eid) {
    int a = blockIdx.y;
    int e = blockIdx.x * 256 + threadIdx.x;
    if (e < EE) {
        int dst = ei[(size_t)a * 2 * EE + EE + e];
        int pos = atomicAdd(&cursor[a * (NN + 1) + dst], 1);
        csr_eid[(size_t)a * EE + pos] = e;
    }
}

// ONE WAVE PER NODE: bitonic sort of the bucket's edge ids (deterministic
// order), resolve src ids, AND compute the 8 per-head edge weights in place.

__global__ __launch_bounds__(256) void sort_src(const int* __restrict__ ei,
                                                const int* __restrict__ offs,
                                                int* __restrict__ csr_eid,
                                                int* __restrict__ csr_src,
                                                const float* __restrict__ asrc,
                                                const float* __restrict__ adst,
                                                float* __restrict__ w_csr) {
    int a = blockIdx.y;
    int wid = threadIdx.x >> 6, l = threadIdx.x & 63;
    int n = blockIdx.x * 4 + wid;
    if (n >= NN) return;
    const int* offsA = offs + a * (NN + 1);
    int beg = offsA[n], end = offsA[n + 1];
    int deg = end - beg;
    int* seg = csr_eid + (size_t)a * EE + beg;
    const int* srcrow = ei + (size_t)a * 2 * EE;  // row 0 = src
    const float* asrcA = asrc + (size_t)a * NN * HH;
    const float* adstA = adst + (size_t)a * NN * HH;
    float4 d0 = *(const float4*)(adstA + (size_t)n * HH);
    float4 d1 = *(const float4*)(adstA + (size_t)n * HH + 4);

    if (deg <= 64) {
        int v = (l < deg) ? seg[l] : 0x7fffffff;
        #pragma unroll
        for (int k = 2; k <= 64; k <<= 1)
            #pragma unroll
            for (int j = k >> 1; j > 0; j >>= 1) {
                int p = __shfl_xor(v, j);
                bool keepMin = (((l & k) == 0) == ((l & j) == 0));
                int mn = min(v, p), mx = max(v, p);
                v = keepMin ? mn : mx;
            }
        if (l < deg) {
            int s = srcrow[v];
            csr_src[(size_t)a * EE + beg + l] = s;
            float4 s0 = *(const float4*)(asrcA + (size_t)s * HH);
            float4 s1 = *(const float4*)(asrcA + (size_t)s * HH + 4);
            float4 w0, w1;
            w0.x = leaky_exp(s0.x + d0.x); w0.y = leaky_exp(s0.y + d0.y);
            w0.z = leaky_exp(s0.z + d0.z); w0.w = leaky_exp(s0.w + d0.w);
            w1.x = leaky_exp(s1.x + d1.x); w1.y = leaky_exp(s1.y + d1.y);
            w1.z = leaky_exp(s1.z + d1.z); w1.w = leaky_exp(s1.w + d1.w);
            float* wp = w_csr + ((size_t)a * EE + beg + l) * HH;
            *(float4*)(wp) = w0;
            *(float4*)(wp + 4) = w1;
        }
    } else {
        // rare fallback (P ~ 1e-24 for Poisson(12.8))
        if (l == 0) {
            for (int i = 1; i < deg; ++i) {
                int key = seg[i];
                int j = i - 1;
                while (j >= 0 && seg[j] > key) { seg[j + 1] = seg[j]; --j; }
                seg[j + 1] = key;
            }
        }
        __builtin_amdgcn_wave_barrier();
        for (int i = l; i < deg; i += 64) {
            int s = srcrow[seg[i]];
            csr_src[(size_t)a * EE + beg + i] = s;
            float4 s0 = *(const float4*)(asrcA + (size_t)s * HH);
            float4 s1 = *(const float4*)(asrcA + (size_t)s * HH + 4);
            float4 w0, w1;
            w0.x = leaky_exp(s0.x + d0.x); w0.y = leaky_exp(s0.y + d0.y);
            w0.z = leaky_exp(s0.z + d0.z); w0.w = leaky_exp(s0.w + d0.w);
            w1.x = leaky_exp(s1.x + d1.x); w1.y = leaky_exp(s1.y + d1.y);
            w1.z = leaky_exp(s1.z + d1.z); w1.w = leaky_exp(s1.w + d1.w);
            float* wp = w_csr + ((size_t)a * EE + beg + i) * HH;
            *(float4*)(wp) = w0;
            *(float4*)(wp + 4) = w1;
        }
    }
}

// ---------- pack x and W1 into MFMA-fragment order (fp16) ----------
// Layout: P[((tile*NT + ks)*4 + frag)*64 + lane] : f16x8

__global__ __launch_bounds__(256) void pack_x(const float* __restrict__ X,
                                              ushort* __restrict__ Xp) {
    int gid = blockIdx.x * 256 + threadIdx.x;
    if (gid >= NBM * NT * 4 * 64) return;
    int l = gid & 63;
    int fr = (gid >> 6) & 3;
    int rest = gid >> 8;
    int ks = rest % NT;
    int bmi = rest / NT;
    int row = bmi * 64 + fr * 16 + (l & 15);
    int k = ks * 32 + (l >> 4) * 8;
    f16x8 o;
    if (row < MM && k + 8 <= DD) {
        float4 v0 = *(const float4*)(X + (size_t)row * DD + k);
        float4 v1 = *(const float4*)(X + (size_t)row * DD + k + 4);
        o[0] = (_Float16)v0.x; o[1] = (_Float16)v0.y;
        o[2] = (_Float16)v0.z; o[3] = (_Float16)v0.w;
        o[4] = (_Float16)v1.x; o[5] = (_Float16)v1.y;
        o[6] = (_Float16)v1.z; o[7] = (_Float16)v1.w;
    } else {
        #pragma unroll
        for (int j = 0; j < 8; ++j)
            o[j] = (row < MM && k + j < DD) ? (_Float16)X[(size_t)row * DD + k + j]
                                            : (_Float16)0.f;
    }
    *(f16x8*)(Xp + (size_t)gid * 8) = o;
}

__global__ __launch_bounds__(256) void pack_w(const float* __restrict__ W,
                                              ushort* __restrict__ Wp) {
    int gid = blockIdx.x * 256 + threadIdx.x;
    if (gid >= HH * NT * 4 * 64) return;
    int l = gid & 63;
    int fc = (gid >> 6) & 3;
    int rest = gid >> 8;
    int ks = rest % NT;
    int head = rest / NT;
    int col = head * 64 + fc * 16 + (l & 15);
    int k = ks * 32 + (l >> 4) * 8;
    f16x8 o;
    #pragma unroll
    for (int j = 0; j < 8; ++j)
        o[j] = (k + j < DD) ? (_Float16)W[(size_t)(k + j) * HC + col] : (_Float16)0.f;
    *(f16x8*)(Wp + (size_t)gid * 8) = o;
}

// ---- fp16 MFMA GEMM: h1 = x @ W1, packed operands, no LDS, no barriers ----
// Wave owns 64 rows x 128 cols (TWO heads): halves A traffic, 32 MFMA per
// fragment set. h1 stored fp8 e4m3.

__global__ __launch_bounds__(256) void gemm_f16(const ushort* __restrict__ Xp,
                                                const ushort* __restrict__ Wp,
                                                const float* __restrict__ att_src1,
                                                const float* __restrict__ att_dst1,
                                                uchar* __restrict__ Hout,
                                                float* __restrict__ asrc,
                                                float* __restrict__ adst) {
    int wid = blockIdx.x * 4 + (threadIdx.x >> 6);
    int bmi = wid >> 2, hp = wid & 3;     // head pair hp -> heads 2hp, 2hp+1
    if (bmi >= NBM) return;
    int bm = bmi * 64;
    int l = threadIdx.x & 63;
    int l16 = l & 15, kg = l >> 4;

    const ushort* Abase = Xp + (size_t)bmi * NT * 2048 + l * 8;
    const ushort* B0 = Wp + (size_t)(hp * 2) * NT * 2048 + l * 8;
    const ushort* B1 = Wp + (size_t)(hp * 2 + 1) * NT * 2048 + l * 8;

    f32x4 zz = {0.f, 0.f, 0.f, 0.f};
    f32x4 acc0[4][4], acc1[4][4];
    #pragma unroll
    for (int i = 0; i < 4; ++i)
        #pragma unroll
        for (int j = 0; j < 4; ++j) { acc0[i][j] = zz; acc1[i][j] = zz; }

    f16x8 aX[4], b0X[4], b1X[4], aY[4], b0Y[4], b1Y[4];
    #pragma unroll
    for (int f = 0; f < 4; ++f) {
        aX[f]  = *(const f16x8*)(Abase + f * 512);
        b0X[f] = *(const f16x8*)(B0 + f * 512);
        b1X[f] = *(const f16x8*)(B1 + f * 512);
    }

    #pragma unroll
    for (int kk = 0; kk < NT; kk += 2) {
        if (kk + 1 < NT) {
            #pragma unroll
            for (int f = 0; f < 4; ++f) {
                aY[f]  = *(const f16x8*)(Abase + (kk + 1) * 2048 + f * 512);
                b0Y[f] = *(const f16x8*)(B0 + (kk + 1) * 2048 + f * 512);
                b1Y[f] = *(const f16x8*)(B1 + (kk + 1) * 2048 + f * 512);
            }
        }
        #pragma unroll
        for (int fr = 0; fr < 4; ++fr)
            #pragma unroll
            for (int fc = 0; fc < 4; ++fc) {
                acc0[fr][fc] = __builtin_amdgcn_mfma_f32_16x16x32_f16(aX[fr], b0X[fc], acc0[fr][fc], 0, 0, 0);
                acc1[fr][fc] = __builtin_amdgcn_mfma_f32_16x16x32_f16(aX[fr], b1X[fc], acc1[fr][fc], 0, 0, 0);
            }
        if (kk + 2 < NT) {
            #pragma unroll
            for (int f = 0; f < 4; ++f) {
                aX[f]  = *(const f16x8*)(Abase + (kk + 2) * 2048 + f * 512);
                b0X[f] = *(const f16x8*)(B0 + (kk + 2) * 2048 + f * 512);
                b1X[f] = *(const f16x8*)(B1 + (kk + 2) * 2048 + f * 512);
            }
        }
        if (kk + 1 < NT) {
            #pragma unroll
            for (int fr = 0; fr < 4; ++fr)
                #pragma unroll
                for (int fc = 0; fc < 4; ++fc) {
                    acc0[fr][fc] = __builtin_amdgcn_mfma_f32_16x16x32_f16(aY[fr], b0Y[fc], acc0[fr][fc], 0, 0, 0);
                    acc1[fr][fc] = __builtin_amdgcn_mfma_f32_16x16x32_f16(aY[fr], b1Y[fc], acc1[fr][fc], 0, 0, 0);
                }
        }
    }

    // ---- epilogue: store h1 (fp8 e4m3), fused alpha_src/alpha_dst, both heads ----
    #pragma unroll
    for (int hd = 0; hd < 2; ++hd) {
        int head = hp * 2 + hd;
        float sv[4], dv[4];
        #pragma unroll
        for (int fc = 0; fc < 4; ++fc) {
            sv[fc] = att_src1[head * 64 + fc * 16 + l16];
            dv[fc] = att_dst1[head * 64 + fc * 16 + l16];
        }
        #pragma unroll
        for (int fr = 0; fr < 4; ++fr) {
            #pragma unroll
            for (int r = 0; r < 4; ++r) {
                int row = bm + fr * 16 + kg * 4 + r;
                bool ok = row < MM;
                float ps = 0.f, pd = 0.f;
                #pragma unroll
                for (int fc = 0; fc < 4; ++fc) {
                    float val = hd == 0 ? acc0[fr][fc][r] : acc1[fr][fc][r];
                    if (ok) {
                        int pk = __builtin_amdgcn_cvt_pk_fp8_f32(val, val, 0, false);
                        Hout[(size_t)row * HC + head * 64 + fc * 16 + l16] = (uchar)(pk & 0xff);
                    }
                    ps = fmaf(val, sv[fc], ps);
                    pd = fmaf(val, dv[fc], pd);
                }
                #pragma unroll
                for (int o = 1; o < 16; o <<= 1) {
                    ps += __shfl_xor(ps, o);
                    pd += __shfl_xor(pd, o);
                }
                if (l16 == 0 && ok) {
                    asrc[(size_t)row * HH + head] = ps;
                    adst[(size_t)row * HH + head] = pd;
                }
            }
        }
    }
}

// ------------- layer-1 aggregation fused with h2 = relu(out+b) @ W2 -------------
// ONE WAVE PER NODE, no LDS, no barriers, NO ds_bpermute: per-edge weight read
// as L1 gather (warmed by the coalesced denominator load); src as broadcast
// load. h1 gathered as fp8 (8 B/lane/row), HW cvt decode; fp32 accumulate.

__global__ __launch_bounds__(256) void layer1_agg(const uchar* __restrict__ h1,
                                                  const float* __restrict__ w_csr,
                                                  const int* __restrict__ offs,
                                                  const int* __restrict__ csr_src,
                                                  const float* __restrict__ bias1,
                                                  const float* __restrict__ W2,
                                                  float* __restrict__ h2) {
    int a = blockIdx.y;
    int wid = threadIdx.x >> 6, l = threadIdx.x & 63;
    int n = blockIdx.x * 4 + wid;
    int gh = l >> 3;          // gather head = l/8 (also edge-slot for denom load)

    const int* offsA = offs + a * (NN + 1);
    int beg = offsA[n], end = offsA[n + 1];
    int deg = end - beg;
    const int* srcs = csr_src + (size_t)a * EE + beg;
    const float* wA = w_csr + ((size_t)a * EE + beg) * HH;
    const uchar* h1A = h1 + (size_t)a * NN * HC;

    float denom = 0.f;
    float acc[8] = {};

    for (int c0 = 0; c0 < deg; c0 += 8) {
        // coalesced chunk load: covers (edge c0+(l>>3), head l&7) -> denom + L1 warm
        float wv = (c0 + gh < deg) ? wA[c0 * 8 + l] : 0.f;
        denom += wv;
        #pragma unroll
        for (int j = 0; j < 8; ++j) {
            if (c0 + j < deg) {
                int sj = srcs[c0 + j];                 // wave-uniform broadcast load
                float wj = wA[(c0 + j) * 8 + gh];      // L1 hit (warmed above)
                uint2 hv = *(const uint2*)(h1A + (size_t)sj * HC + (l << 3));
                f32x2 p0 = __builtin_amdgcn_cvt_pk_f32_fp8((int)hv.x, false);
                f32x2 p1 = __builtin_amdgcn_cvt_pk_f32_fp8((int)hv.x, true);
                f32x2 p2 = __builtin_amdgcn_cvt_pk_f32_fp8((int)hv.y, false);
                f32x2 p3 = __builtin_amdgcn_cvt_pk_f32_fp8((int)hv.y, true);
                acc[0] = fmaf(wj, p0[0], acc[0]);
                acc[1] = fmaf(wj, p0[1], acc[1]);
                acc[2] = fmaf(wj, p1[0], acc[2]);
                acc[3] = fmaf(wj, p1[1], acc[3]);
                acc[4] = fmaf(wj, p2[0], acc[4]);
                acc[5] = fmaf(wj, p2[1], acc[5]);
                acc[6] = fmaf(wj, p3[0], acc[6]);
                acc[7] = fmaf(wj, p3[1], acc[7]);
            }
        }
    }
    // denom: lane l holds partial for head (l&7); fold edge-slots (stride 8..32)
    #pragma unroll
    for (int o = 8; o < 64; o <<= 1) denom += __shfl_xor(denom, o);
    float dn = __shfl(denom, gh);        // lane gh holds denom[head gh]
    float inv = 1.f / (dn + 1e-16f);

    int cb = l * 8;
    float4 b0 = *(const float4*)(bias1 + cb);
    float4 b1 = *(const float4*)(bias1 + cb + 4);
    float4 w0 = *(const float4*)(W2 + cb);
    float4 w1 = *(const float4*)(W2 + cb + 4);
    float bz[8] = {b0.x, b0.y, b0.z, b0.w, b1.x, b1.y, b1.z, b1.w};
    float wz[8] = {w0.x, w0.y, w0.z, w0.w, w1.x, w1.y, w1.z, w1.w};
    float p = 0.f;
    #pragma unroll
    for (int k = 0; k < 8; ++k) {
        float z = fmaf(acc[k], inv, bz[k]);
        z = z > 0.f ? z : 0.f;
        p = fmaf(z, wz[k], p);
    }
    #pragma unroll
    for (int o = 1; o < 64; o <<= 1) p += __shfl_xor(p, o);
    if (l == 0) h2[(size_t)a * NN + n] = p;
}

// ---------------- layer 2 (scalar per node) -> proba partials ----------------

#define L2GRID 40

__global__ __launch_bounds__(256) void layer2_proba(const float* __restrict__ h2,
                                                    const int* __restrict__ offs,
                                                    const int* __restrict__ csr_src,
                                                    const float* __restrict__ att_src2,
                                                    const float* __restrict__ att_dst2,
                                                    const float* __restrict__ bias2,
                                                    float* __restrict__ partials) {
    int a = blockIdx.y;
    int n = blockIdx.x * 256 + threadIdx.x;
    float out2 = 0.f;
    if (n < NN) {
        const int* offsA = offs + a * (NN + 1);
        const int* srcs = csr_src + (size_t)a * EE;
        const float* h2A = h2 + (size_t)a * NN;
        float as2 = att_src2[0], ad2 = att_dst2[0];
        int beg = offsA[n], end = offsA[n + 1];
        float adn = h2A[n] * ad2;
        float denom = 0.f, accv = 0.f;
        for (int i = beg; i < end; ++i) {
            float hs = h2A[srcs[i]];
            float v = fmaf(hs, as2, adn);
            v = v > 0.f ? v : 0.2f * v;
            float w = __expf(v);
            denom += w;
            accv = fmaf(w, hs, accv);
        }
        out2 = accv / (denom + 1e-16f) + bias2[0];
    }
    __shared__ float red[256];
    red[threadIdx.x] = out2;
    __syncthreads();
    for (int s = 128; s > 0; s >>= 1) {
        if (threadIdx.x < s) red[threadIdx.x] += red[threadIdx.x + s];
        __syncthreads();
    }
    if (threadIdx.x == 0) partials[a * L2GRID + blockIdx.x] = red[0];
}

__global__ __launch_bounds__(256) void finalize_proba(const float* __restrict__ partials,
                                                      float* __restrict__ out,
                                                      int* __restrict__ best) {
    int tid = threadIdx.x;
    __shared__ float red[256];
    red[tid] = (tid < AA * L2GRID) ? partials[tid] : 0.f;
    __syncthreads();
    if (tid == 0) {
        float pv[AA];
        for (int a = 0; a < AA; ++a) {
            float s = 0.f;
            for (int i = 0; i < L2GRID; ++i) s += red[a * L2GRID + i];
            pv[a] = s / (float)NN;
            out[a] = pv[a];
        }
        int b = 0;
        for (int a = 1; a < AA; ++a)
            if (pv[a] > pv[b]) b = a;
        *best = b;
    }
}

__global__ void write_sel(const int* __restrict__ cnt, const int* __restrict__ best,
                          float* __restrict__ out) {
    int n = blockIdx.x * 256 + threadIdx.x;
    if (n < NN) out[AA + n] = (cnt[(*best) * NN + n] > 0) ? 1.0f : 0.0f;
}

// ---------------- launch ----------------

extern "C" void kernel_launch(void* const* d_in, const int* in_sizes, int n_in,
                              void* d_out, int out_size, void* d_ws, size_t ws_size,
                              hipStream_t stream) {
    const float* x        = (const float*)d_in[0];
    const int*   ei       = (const int*)d_in[1];
    const float* W1       = (const float*)d_in[2];
    const float* att_src1 = (const float*)d_in[3];
    const float* att_dst1 = (const float*)d_in[4];
    const float* bias1    = (const float*)d_in[5];
    const float* W2       = (const float*)d_in[6];
    const float* att_src2 = (const float*)d_in[7];
    const float* att_dst2 = (const float*)d_in[8];
    const float* bias2    = (const float*)d_in[9];
    float* out = (float*)d_out;

    char* ws = (char*)d_ws;
    size_t off = 0;
    auto alloc = [&](size_t bytes) {
        size_t cur = off;
        off += (bytes + 255) & ~(size_t)255;
        return cur;
    };
    uchar*  h1      = (uchar*)(ws + alloc(sizeof(uchar) * (size_t)MM * HC));           // 25.6 MB
    ushort* xp      = (ushort*)(ws + alloc(sizeof(ushort) * (size_t)NBM * NT * 2048)); // 32 MB
    float*  asrc    = (float*)(ws + alloc(sizeof(float) * (size_t)MM * HH));
    float*  adst    = (float*)(ws + alloc(sizeof(float) * (size_t)MM * HH));
    float*  h2      = (float*)(ws + alloc(sizeof(float) * (size_t)MM));
    int*    cnt     = (int*)(ws + alloc(sizeof(int) * (size_t)AA * NN));
    int*    offs    = (int*)(ws + alloc(sizeof(int) * (size_t)AA * (NN + 1)));
    int*    cursor  = (int*)(ws + alloc(sizeof(int) * (size_t)AA * (NN + 1)));
    int*    bsum    = (int*)(ws + alloc(sizeof(int) * (size_t)AA * SCB));
    int*    boff    = (int*)(ws + alloc(sizeof(int) * (size_t)AA * SCB));
    int*    csr_eid = (int*)(ws + alloc(sizeof(int) * (size_t)AA * EE));
    int*    csr_src = (int*)(ws + alloc(sizeof(int) * (size_t)AA * EE));
    float*  w_csr   = (float*)(ws + alloc(sizeof(float) * (size_t)AA * EE * HH));      // 20.5 MB
    float*  partials= (float*)(ws + alloc(sizeof(float) * AA * L2GRID));
    int*    best    = (int*)(ws + alloc(sizeof(int) * 16));
    ushort* wp      = (ushort*)(ws + alloc(sizeof(ushort) * (size_t)HH * NT * 2048)); // 320 KB
    (void)ws_size; (void)in_sizes; (void)n_in; (void)out_size;

    pack_w<<<dim3((HH * NT * 256 + 255) / 256), dim3(256), 0, stream>>>(W1, wp);
    pack_x<<<dim3((NBM * NT * 256 + 255) / 256), dim3(256), 0, stream>>>(x, xp);

    hipMemsetAsync(cnt, 0, sizeof(int) * (size_t)AA * NN, stream);
    count_edges<<<dim3(EE / 256, AA), dim3(256), 0, stream>>>(ei, cnt);
    scan_bsum<<<dim3(SCB, AA), dim3(256), 0, stream>>>(cnt, bsum);
    scan_bscan<<<dim3(AA), dim3(64), 0, stream>>>(bsum, boff, offs);
    scan_final<<<dim3(SCB, AA), dim3(256), 0, stream>>>(cnt, boff, offs, cursor);
    scatter_edges<<<dim3(EE / 256, AA), dim3(256), 0, stream>>>(ei, cursor, csr_eid);

    // gemm first: sort_src consumes asrc/adst for fused edge-weight computation
    gemm_f16<<<dim3(NBM), dim3(256), 0, stream>>>(
        xp, wp, att_src1, att_dst1, h1, asrc, adst);

    sort_src<<<dim3(NN / 4, AA), dim3(256), 0, stream>>>(ei, offs, csr_eid, csr_src,
                                                         asrc, adst, w_csr);

    layer1_agg<<<dim3(NN / 4, AA), dim3(256), 0, stream>>>(h1, w_csr, offs, csr_src,
                                                           bias1, W2, h2);

    layer2_proba<<<dim3(L2GRID, AA), dim3(256), 0, stream>>>(h2, offs, csr_src,
                                                             att_src2, att_dst2, bias2,
                                                             partials);

    finalize_proba<<<dim3(1), dim3(256), 0, stream>>>(partials, out, best);
    write_sel<<<dim3((NN + 255) / 256), dim3(256), 0, stream>>>(cnt, best, out);
}

// Round 15
// 255.829 us; speedup vs baseline: 1.1231x; 1.1231x over previous
//
#include <hip/hip_runtime.h>
#include <hip/hip_bf16.h>
#include <math.h>

#define NN 10000
#define EE 128000
#define AA 5
#define DD 300
#define HH 8
#define CC 64
#define HC 512
#define MM (AA*NN)   // 50000 rows total
#define KP 320       // K padded to multiple of 32
#define NT (KP / 32) // 10 K-steps
#define NBM ((MM + 63) / 64)   // 782 row-tiles
#define SCB 40       // scan: blocks per answer
#define SCN 250      // scan: nodes per block  (SCB*SCN == NN)

typedef __attribute__((ext_vector_type(8))) _Float16 f16x8;
typedef __attribute__((ext_vector_type(4))) float f32x4;
typedef __attribute__((ext_vector_type(2))) float f32x2;
typedef unsigned short ushort;
typedef unsigned char uchar;

__device__ __forceinline__ ushort f2bf(float f) {
    unsigned u = __float_as_uint(f);
    unsigned r = u + 0x7fffu + ((u >> 16) & 1u);   // RN-even
    return (ushort)(r >> 16);
}
__device__ __forceinline__ float bf2f(ushort h) {
    return __uint_as_float(((unsigned)h) << 16);
}
__device__ __forceinline__ float leaky_exp(float v) {
    v = v > 0.f ? v : 0.2f * v;
    return __expf(v);
}

// ---------------- CSR build ----------------

__global__ void count_edges(const int* __restrict__ ei, int* __restrict__ cnt) {
    int a = blockIdx.y;
    int e = blockIdx.x * 256 + threadIdx.x;
    if (e < EE) {
        int dst = ei[(size_t)a * 2 * EE + EE + e];
        atomicAdd(&cnt[a * NN + dst], 1);
    }
}

// --- hierarchical exclusive scan of cnt -> offs, cursor (3 small kernels) ---

__global__ __launch_bounds__(256) void scan_bsum(const int* __restrict__ cnt,
                                                 int* __restrict__ bsum) {
    int a = blockIdx.y, b = blockIdx.x;
    int l = threadIdx.x;
    int v = (l < SCN) ? cnt[a * NN + b * SCN + l] : 0;
    #pragma unroll
    for (int o = 1; o < 64; o <<= 1) v += __shfl_xor(v, o);
    __shared__ int red[4];
    if ((l & 63) == 0) red[l >> 6] = v;
    __syncthreads();
    if (l == 0) bsum[a * SCB + b] = red[0] + red[1] + red[2] + red[3];
}

__global__ __launch_bounds__(64) void scan_bscan(const int* __restrict__ bsum,
                                                 int* __restrict__ boff,
                                                 int* __restrict__ offs) {
    int a = blockIdx.x;
    int l = threadIdx.x;
    int v = (l < SCB) ? bsum[a * SCB + l] : 0;
    int sc = v;
    #pragma unroll
    for (int o = 1; o < 64; o <<= 1) {
        int u = __shfl_up(sc, o);
        if (l >= o) sc += u;
    }
    if (l < SCB) boff[a * SCB + l] = sc - v;
    if (l == 63) offs[a * (NN + 1) + NN] = sc;   // grand total
}

__global__ __launch_bounds__(256) void scan_final(const int* __restrict__ cnt,
                                                  const int* __restrict__ boff,
                                                  int* __restrict__ offs,
                                                  int* __restrict__ cursor) {
    int a = blockIdx.y, b = blockIdx.x;
    int l = threadIdx.x;
    int i = b * SCN + l;
    int v = (l < SCN) ? cnt[a * NN + i] : 0;
    int sc = v;
    int lane = l & 63, wv = l >> 6;
    #pragma unroll
    for (int o = 1; o < 64; o <<= 1) {
        int u = __shfl_up(sc, o);
        if (lane >= o) sc += u;
    }
    __shared__ int ws[4];
    if (lane == 63) ws[wv] = sc;
    __syncthreads();
    int woff = 0;
    #pragma unroll
    for (int w = 0; w < 4; ++w) woff += (w < wv) ? ws[w] : 0;
    if (l < SCN) {
        int o = boff[a * SCB + b] + woff + sc - v;
        offs[a * (NN + 1) + i] = o;
        cursor[a * (NN + 1) + i] = o;
    }
}

__global__ void scatter_edges(const int* __restrict__ ei, int* __restrict__ cursor,
                              int* __restrict__ csr_eid) {
    int a = blockIdx.y;
    int e = blockIdx.x * 256 + threadIdx.x;
    if (e < EE) {
        int dst = ei[(size_t)a * 2 * EE + EE + e];
        int pos = atomicAdd(&cursor[a * (NN + 1) + dst], 1);
        csr_eid[(size_t)a * EE + pos] = e;
    }
}

// ONE WAVE PER NODE: bitonic sort of the bucket's edge ids (deterministic
// order), resolve src ids, AND compute the 8 per-head edge weights in place.

__global__ __launch_bounds__(256) void sort_src(const int* __restrict__ ei,
                                                const int* __restrict__ offs,
                                                int* __restrict__ csr_eid,
                                                int* __restrict__ csr_src,
                                                const float* __restrict__ asrc,
                                                const float* __restrict__ adst,
                                                float* __restrict__ w_csr) {
    int a = blockIdx.y;
    int wid = threadIdx.x >> 6, l = threadIdx.x & 63;
    int n = blockIdx.x * 4 + wid;
    if (n >= NN) return;
    const int* offsA = offs + a * (NN + 1);
    int beg = offsA[n], end = offsA[n + 1];
    int deg = end - beg;
    int* seg = csr_eid + (size_t)a * EE + beg;
    const int* srcrow = ei + (size_t)a * 2 * EE;  // row 0 = src
    const float* asrcA = asrc + (size_t)a * NN * HH;
    const float* adstA = adst + (size_t)a * NN * HH;
    float4 d0 = *(const float4*)(adstA + (size_t)n * HH);
    float4 d1 = *(const float4*)(adstA + (size_t)n * HH + 4);

    if (deg <= 64) {
        int v = (l < deg) ? seg[l] : 0x7fffffff;
        #pragma unroll
        for (int k = 2; k <= 64; k <<= 1)
            #pragma unroll
            for (int j = k >> 1; j > 0; j >>= 1) {
                int p = __shfl_xor(v, j);
                bool keepMin = (((l & k) == 0) == ((l & j) == 0));
                int mn = min(v, p), mx = max(v, p);
                v = keepMin ? mn : mx;
            }
        if (l < deg) {
            int s = srcrow[v];
            csr_src[(size_t)a * EE + beg + l] = s;
            float4 s0 = *(const float4*)(asrcA + (size_t)s * HH);
            float4 s1 = *(const float4*)(asrcA + (size_t)s * HH + 4);
            float4 w0, w1;
            w0.x = leaky_exp(s0.x + d0.x); w0.y = leaky_exp(s0.y + d0.y);
            w0.z = leaky_exp(s0.z + d0.z); w0.w = leaky_exp(s0.w + d0.w);
            w1.x = leaky_exp(s1.x + d1.x); w1.y = leaky_exp(s1.y + d1.y);
            w1.z = leaky_exp(s1.z + d1.z); w1.w = leaky_exp(s1.w + d1.w);
            float* wp = w_csr + ((size_t)a * EE + beg + l) * HH;
            *(float4*)(wp) = w0;
            *(float4*)(wp + 4) = w1;
        }
    } else {
        // rare fallback (P ~ 1e-24 for Poisson(12.8))
        if (l == 0) {
            for (int i = 1; i < deg; ++i) {
                int key = seg[i];
                int j = i - 1;
                while (j >= 0 && seg[j] > key) { seg[j + 1] = seg[j]; --j; }
                seg[j + 1] = key;
            }
        }
        __builtin_amdgcn_wave_barrier();
        for (int i = l; i < deg; i += 64) {
            int s = srcrow[seg[i]];
            csr_src[(size_t)a * EE + beg + i] = s;
            float4 s0 = *(const float4*)(asrcA + (size_t)s * HH);
            float4 s1 = *(const float4*)(asrcA + (size_t)s * HH + 4);
            float4 w0, w1;
            w0.x = leaky_exp(s0.x + d0.x); w0.y = leaky_exp(s0.y + d0.y);
            w0.z = leaky_exp(s0.z + d0.z); w0.w = leaky_exp(s0.w + d0.w);
            w1.x = leaky_exp(s1.x + d1.x); w1.y = leaky_exp(s1.y + d1.y);
            w1.z = leaky_exp(s1.z + d1.z); w1.w = leaky_exp(s1.w + d1.w);
            float* wp = w_csr + ((size_t)a * EE + beg + i) * HH;
            *(float4*)(wp) = w0;
            *(float4*)(wp + 4) = w1;
        }
    }
}

// ---------- pack x and W1 into MFMA-fragment order (fp16) ----------
// Layout: P[((tile*NT + ks)*4 + frag)*64 + lane] : f16x8

__global__ __launch_bounds__(256) void pack_x(const float* __restrict__ X,
                                              ushort* __restrict__ Xp) {
    int gid = blockIdx.x * 256 + threadIdx.x;
    if (gid >= NBM * NT * 4 * 64) return;
    int l = gid & 63;
    int fr = (gid >> 6) & 3;
    int rest = gid >> 8;
    int ks = rest % NT;
    int bmi = rest / NT;
    int row = bmi * 64 + fr * 16 + (l & 15);
    int k = ks * 32 + (l >> 4) * 8;
    f16x8 o;
    if (row < MM && k + 8 <= DD) {
        float4 v0 = *(const float4*)(X + (size_t)row * DD + k);
        float4 v1 = *(const float4*)(X + (size_t)row * DD + k + 4);
        o[0] = (_Float16)v0.x; o[1] = (_Float16)v0.y;
        o[2] = (_Float16)v0.z; o[3] = (_Float16)v0.w;
        o[4] = (_Float16)v1.x; o[5] = (_Float16)v1.y;
        o[6] = (_Float16)v1.z; o[7] = (_Float16)v1.w;
    } else {
        #pragma unroll
        for (int j = 0; j < 8; ++j)
            o[j] = (row < MM && k + j < DD) ? (_Float16)X[(size_t)row * DD + k + j]
                                            : (_Float16)0.f;
    }
    *(f16x8*)(Xp + (size_t)gid * 8) = o;
}

__global__ __launch_bounds__(256) void pack_w(const float* __restrict__ W,
                                              ushort* __restrict__ Wp) {
    int gid = blockIdx.x * 256 + threadIdx.x;
    if (gid >= HH * NT * 4 * 64) return;
    int l = gid & 63;
    int fc = (gid >> 6) & 3;
    int rest = gid >> 8;
    int ks = rest % NT;
    int head = rest / NT;
    int col = head * 64 + fc * 16 + (l & 15);
    int k = ks * 32 + (l >> 4) * 8;
    f16x8 o;
    #pragma unroll
    for (int j = 0; j < 8; ++j)
        o[j] = (k + j < DD) ? (_Float16)W[(size_t)(k + j) * HC + col] : (_Float16)0.f;
    *(f16x8*)(Wp + (size_t)gid * 8) = o;
}

// ---- fp16 MFMA GEMM: h1 = x @ W1, packed operands, no LDS, no barriers ----
// Wave owns 64 rows x 64 cols (one head). Every fragment load is a dense,
// coalesced 1KB read: base + ks*2048 + frag*512 elements. (round-13 version)

__global__ __launch_bounds__(256) void gemm_f16(const ushort* __restrict__ Xp,
                                                const ushort* __restrict__ Wp,
                                                const float* __restrict__ att_src1,
                                                const float* __restrict__ att_dst1,
                                                uchar* __restrict__ Hout,
                                                float* __restrict__ asrc,
                                                float* __restrict__ adst) {
    int wid = blockIdx.x * 4 + (threadIdx.x >> 6);
    int bmi = wid >> 3, head = wid & 7;
    if (bmi >= NBM) return;
    int bm = bmi * 64;
    int l = threadIdx.x & 63;
    int l16 = l & 15, kg = l >> 4;

    const ushort* Abase = Xp + (size_t)bmi * NT * 2048 + l * 8;
    const ushort* Bbase = Wp + (size_t)head * NT * 2048 + l * 8;

    f32x4 zz = {0.f, 0.f, 0.f, 0.f};
    f32x4 acc[4][4];
    #pragma unroll
    for (int i = 0; i < 4; ++i)
        #pragma unroll
        for (int j = 0; j < 4; ++j) acc[i][j] = zz;

    f16x8 aX[4], bX[4], aY[4], bY[4];
    #pragma unroll
    for (int f = 0; f < 4; ++f) {
        aX[f] = *(const f16x8*)(Abase + f * 512);
        bX[f] = *(const f16x8*)(Bbase + f * 512);
    }

    #pragma unroll
    for (int kk = 0; kk < NT; kk += 2) {
        if (kk + 1 < NT) {
            #pragma unroll
            for (int f = 0; f < 4; ++f) {
                aY[f] = *(const f16x8*)(Abase + (kk + 1) * 2048 + f * 512);
                bY[f] = *(const f16x8*)(Bbase + (kk + 1) * 2048 + f * 512);
            }
        }
        #pragma unroll
        for (int fr = 0; fr < 4; ++fr)
            #pragma unroll
            for (int fc = 0; fc < 4; ++fc)
                acc[fr][fc] = __builtin_amdgcn_mfma_f32_16x16x32_f16(aX[fr], bX[fc], acc[fr][fc], 0, 0, 0);
        if (kk + 2 < NT) {
            #pragma unroll
            for (int f = 0; f < 4; ++f) {
                aX[f] = *(const f16x8*)(Abase + (kk + 2) * 2048 + f * 512);
                bX[f] = *(const f16x8*)(Bbase + (kk + 2) * 2048 + f * 512);
            }
        }
        if (kk + 1 < NT) {
            #pragma unroll
            for (int fr = 0; fr < 4; ++fr)
                #pragma unroll
                for (int fc = 0; fc < 4; ++fc)
                    acc[fr][fc] = __builtin_amdgcn_mfma_f32_16x16x32_f16(aY[fr], bY[fc], acc[fr][fc], 0, 0, 0);
        }
    }

    // ---- epilogue: store h1 (fp8 e4m3), fused alpha_src/alpha_dst ----
    float sv[4], dv[4];
    #pragma unroll
    for (int fc = 0; fc < 4; ++fc) {
        sv[fc] = att_src1[head * 64 + fc * 16 + l16];
        dv[fc] = att_dst1[head * 64 + fc * 16 + l16];
    }
    #pragma unroll
    for (int fr = 0; fr < 4; ++fr) {
        #pragma unroll
        for (int r = 0; r < 4; ++r) {
            int row = bm + fr * 16 + kg * 4 + r;
            bool ok = row < MM;
            float ps = 0.f, pd = 0.f;
            #pragma unroll
            for (int fc = 0; fc < 4; ++fc) {
                float val = acc[fr][fc][r];
                if (ok) {
                    int pk = __builtin_amdgcn_cvt_pk_fp8_f32(val, val, 0, false);
                    Hout[(size_t)row * HC + head * 64 + fc * 16 + l16] = (uchar)(pk & 0xff);
                }
                ps = fmaf(val, sv[fc], ps);
                pd = fmaf(val, dv[fc], pd);
            }
            #pragma unroll
            for (int o = 1; o < 16; o <<= 1) {
                ps += __shfl_xor(ps, o);
                pd += __shfl_xor(pd, o);
            }
            if (l16 == 0 && ok) {
                asrc[(size_t)row * HH + head] = ps;
                adst[(size_t)row * HH + head] = pd;
            }
        }
    }
}

// ------------- layer-1 aggregation fused with h2 = relu(out+b) @ W2 -------------
// ONE WAVE PER NODE, no LDS, no barriers, NO ds_bpermute: per-edge weight read
// as L1 gather (warmed by the coalesced denominator load); src as broadcast
// load. h1 gathered as fp8 (8 B/lane/row), HW cvt decode; fp32 accumulate.

__global__ __launch_bounds__(256) void layer1_agg(const uchar* __restrict__ h1,
                                                  const float* __restrict__ w_csr,
                                                  const int* __restrict__ offs,
                                                  const int* __restrict__ csr_src,
                                                  const float* __restrict__ bias1,
                                                  const float* __restrict__ W2,
                                                  float* __restrict__ h2) {
    int a = blockIdx.y;
    int wid = threadIdx.x >> 6, l = threadIdx.x & 63;
    int n = blockIdx.x * 4 + wid;
    int gh = l >> 3;          // gather head = l/8 (also edge-slot for denom load)

    const int* offsA = offs + a * (NN + 1);
    int beg = offsA[n], end = offsA[n + 1];
    int deg = end - beg;
    const int* srcs = csr_src + (size_t)a * EE + beg;
    const float* wA = w_csr + ((size_t)a * EE + beg) * HH;
    const uchar* h1A = h1 + (size_t)a * NN * HC;

    float denom = 0.f;
    float acc[8] = {};

    for (int c0 = 0; c0 < deg; c0 += 8) {
        // coalesced chunk load: covers (edge c0+(l>>3), head l&7) -> denom + L1 warm
        float wv = (c0 + gh < deg) ? wA[c0 * 8 + l] : 0.f;
        denom += wv;
        #pragma unroll
        for (int j = 0; j < 8; ++j) {
            if (c0 + j < deg) {
                int sj = srcs[c0 + j];                 // wave-uniform broadcast load
                float wj = wA[(c0 + j) * 8 + gh];      // L1 hit (warmed above)
                uint2 hv = *(const uint2*)(h1A + (size_t)sj * HC + (l << 3));
                f32x2 p0 = __builtin_amdgcn_cvt_pk_f32_fp8((int)hv.x, false);
                f32x2 p1 = __builtin_amdgcn_cvt_pk_f32_fp8((int)hv.x, true);
                f32x2 p2 = __builtin_amdgcn_cvt_pk_f32_fp8((int)hv.y, false);
                f32x2 p3 = __builtin_amdgcn_cvt_pk_f32_fp8((int)hv.y, true);
                acc[0] = fmaf(wj, p0[0], acc[0]);
                acc[1] = fmaf(wj, p0[1], acc[1]);
                acc[2] = fmaf(wj, p1[0], acc[2]);
                acc[3] = fmaf(wj, p1[1], acc[3]);
                acc[4] = fmaf(wj, p2[0], acc[4]);
                acc[5] = fmaf(wj, p2[1], acc[5]);
                acc[6] = fmaf(wj, p3[0], acc[6]);
                acc[7] = fmaf(wj, p3[1], acc[7]);
            }
        }
    }
    // denom: lane l holds partial for head (l&7); fold edge-slots (stride 8..32)
    #pragma unroll
    for (int o = 8; o < 64; o <<= 1) denom += __shfl_xor(denom, o);
    float dn = __shfl(denom, gh);        // lane gh holds denom[head gh]
    float inv = 1.f / (dn + 1e-16f);

    int cb = l * 8;
    float4 b0 = *(const float4*)(bias1 + cb);
    float4 b1 = *(const float4*)(bias1 + cb + 4);
    float4 w0 = *(const float4*)(W2 + cb);
    float4 w1 = *(const float4*)(W2 + cb + 4);
    float bz[8] = {b0.x, b0.y, b0.z, b0.w, b1.x, b1.y, b1.z, b1.w};
    float wz[8] = {w0.x, w0.y, w0.z, w0.w, w1.x, w1.y, w1.z, w1.w};
    float p = 0.f;
    #pragma unroll
    for (int k = 0; k < 8; ++k) {
        float z = fmaf(acc[k], inv, bz[k]);
        z = z > 0.f ? z : 0.f;
        p = fmaf(z, wz[k], p);
    }
    #pragma unroll
    for (int o = 1; o < 64; o <<= 1) p += __shfl_xor(p, o);
    if (l == 0) h2[(size_t)a * NN + n] = p;
}

// ---------------- layer 2 (scalar per node) -> proba partials ----------------

#define L2GRID 40

__global__ __launch_bounds__(256) void layer2_proba(const float* __restrict__ h2,
                                                    const int* __restrict__ offs,
                                                    const int* __restrict__ csr_src,
                                                    const float* __restrict__ att_src2,
                                                    const float* __restrict__ att_dst2,
                                                    const float* __restrict__ bias2,
                                                    float* __restrict__ partials) {
    int a = blockIdx.y;
    int n = blockIdx.x * 256 + threadIdx.x;
    float out2 = 0.f;
    if (n < NN) {
        const int* offsA = offs + a * (NN + 1);
        const int* srcs = csr_src + (size_t)a * EE;
        const float* h2A = h2 + (size_t)a * NN;
        float as2 = att_src2[0], ad2 = att_dst2[0];
        int beg = offsA[n], end = offsA[n + 1];
        float adn = h2A[n] * ad2;
        float denom = 0.f, accv = 0.f;
        for (int i = beg; i < end; ++i) {
            float hs = h2A[srcs[i]];
            float v = fmaf(hs, as2, adn);
            v = v > 0.f ? v : 0.2f * v;
            float w = __expf(v);
            denom += w;
            accv = fmaf(w, hs, accv);
        }
        out2 = accv / (denom + 1e-16f) + bias2[0];
    }
    __shared__ float red[256];
    red[threadIdx.x] = out2;
    __syncthreads();
    for (int s = 128; s > 0; s >>= 1) {
        if (threadIdx.x < s) red[threadIdx.x] += red[threadIdx.x + s];
        __syncthreads();
    }
    if (threadIdx.x == 0) partials[a * L2GRID + blockIdx.x] = red[0];
}

__global__ __launch_bounds__(256) void finalize_proba(const float* __restrict__ partials,
                                                      float* __restrict__ out,
                                                      int* __restrict__ best) {
    int tid = threadIdx.x;
    __shared__ float red[256];
    red[tid] = (tid < AA * L2GRID) ? partials[tid] : 0.f;
    __syncthreads();
    if (tid == 0) {
        float pv[AA];
        for (int a = 0; a < AA; ++a) {
            float s = 0.f;
            for (int i = 0; i < L2GRID; ++i) s += red[a * L2GRID + i];
            pv[a] = s / (float)NN;
            out[a] = pv[a];
        }
        int b = 0;
        for (int a = 1; a < AA; ++a)
            if (pv[a] > pv[b]) b = a;
        *best = b;
    }
}

__global__ void write_sel(const int* __restrict__ cnt, const int* __restrict__ best,
                          float* __restrict__ out) {
    int n = blockIdx.x * 256 + threadIdx.x;
    if (n < NN) out[AA + n] = (cnt[(*best) * NN + n] > 0) ? 1.0f : 0.0f;
}

// ---------------- launch ----------------

extern "C" void kernel_launch(void* const* d_in, const int* in_sizes, int n_in,
                              void* d_out, int out_size, void* d_ws, size_t ws_size,
                              hipStream_t stream) {
    const float* x        = (const float*)d_in[0];
    const int*   ei       = (const int*)d_in[1];
    const float* W1       = (const float*)d_in[2];
    const float* att_src1 = (const float*)d_in[3];
    const float* att_dst1 = (const float*)d_in[4];
    const float* bias1    = (const float*)d_in[5];
    const float* W2       = (const float*)d_in[6];
    const float* att_src2 = (const float*)d_in[7];
    const float* att_dst2 = (const float*)d_in[8];
    const float* bias2    = (const float*)d_in[9];
    float* out = (float*)d_out;

    char* ws = (char*)d_ws;
    size_t off = 0;
    auto alloc = [&](size_t bytes) {
        size_t cur = off;
        off += (bytes + 255) & ~(size_t)255;
        return cur;
    };
    uchar*  h1      = (uchar*)(ws + alloc(sizeof(uchar) * (size_t)MM * HC));           // 25.6 MB
    ushort* xp      = (ushort*)(ws + alloc(sizeof(ushort) * (size_t)NBM * NT * 2048)); // 32 MB
    float*  asrc    = (float*)(ws + alloc(sizeof(float) * (size_t)MM * HH));
    float*  adst    = (float*)(ws + alloc(sizeof(float) * (size_t)MM * HH));
    float*  h2      = (float*)(ws + alloc(sizeof(float) * (size_t)MM));
    int*    cnt     = (int*)(ws + alloc(sizeof(int) * (size_t)AA * NN));
    int*    offs    = (int*)(ws + alloc(sizeof(int) * (size_t)AA * (NN + 1)));
    int*    cursor  = (int*)(ws + alloc(sizeof(int) * (size_t)AA * (NN + 1)));
    int*    bsum    = (int*)(ws + alloc(sizeof(int) * (size_t)AA * SCB));
    int*    boff    = (int*)(ws + alloc(sizeof(int) * (size_t)AA * SCB));
    int*    csr_eid = (int*)(ws + alloc(sizeof(int) * (size_t)AA * EE));
    int*    csr_src = (int*)(ws + alloc(sizeof(int) * (size_t)AA * EE));
    float*  w_csr   = (float*)(ws + alloc(sizeof(float) * (size_t)AA * EE * HH));      // 20.5 MB
    float*  partials= (float*)(ws + alloc(sizeof(float) * AA * L2GRID));
    int*    best    = (int*)(ws + alloc(sizeof(int) * 16));
    ushort* wp      = (ushort*)(ws + alloc(sizeof(ushort) * (size_t)HH * NT * 2048)); // 320 KB
    (void)ws_size; (void)in_sizes; (void)n_in; (void)out_size;

    pack_w<<<dim3((HH * NT * 256 + 255) / 256), dim3(256), 0, stream>>>(W1, wp);
    pack_x<<<dim3((NBM * NT * 256 + 255) / 256), dim3(256), 0, stream>>>(x, xp);

    hipMemsetAsync(cnt, 0, sizeof(int) * (size_t)AA * NN, stream);
    count_edges<<<dim3(EE / 256, AA), dim3(256), 0, stream>>>(ei, cnt);
    scan_bsum<<<dim3(SCB, AA), dim3(256), 0, stream>>>(cnt, bsum);
    scan_bscan<<<dim3(AA), dim3(64), 0, stream>>>(bsum, boff, offs);
    scan_final<<<dim3(SCB, AA), dim3(256), 0, stream>>>(cnt, boff, offs, cursor);
    scatter_edges<<<dim3(EE / 256, AA), dim3(256), 0, stream>>>(ei, cursor, csr_eid);

    // gemm first: sort_src consumes asrc/adst for fused edge-weight computation
    gemm_f16<<<dim3((NBM * 8 + 3) / 4), dim3(256), 0, stream>>>(
        xp, wp, att_src1, att_dst1, h1, asrc, adst);

    sort_src<<<dim3(NN / 4, AA), dim3(256), 0, stream>>>(ei, offs, csr_eid, csr_src,
                                                         asrc, adst, w_csr);

    layer1_agg<<<dim3(NN / 4, AA), dim3(256), 0, stream>>>(h1, w_csr, offs, csr_src,
                                                           bias1, W2, h2);

    layer2_proba<<<dim3(L2GRID, AA), dim3(256), 0, stream>>>(h2, offs, csr_src,
                                                             att_src2, att_dst2, bias2,
                                                             partials);

    finalize_proba<<<dim3(1), dim3(256), 0, stream>>>(partials, out, best);
    write_sel<<<dim3((NN + 255) / 256), dim3(256), 0, stream>>>(cnt, best, out);
}

// Round 16
// 235.910 us; speedup vs baseline: 1.2180x; 1.0844x over previous
//
#include <hip/hip_runtime.h>
#include <hip/hip_bf16.h>
#include <math.h>

#define NN 10000
#define EE 128000
#define AA 5
#define DD 300
#define HH 8
#define CC 64
#define HC 512
#define MM (AA*NN)   // 50000 rows total
#define KP 320       // K padded to multiple of 32
#define NT (KP / 32) // 10 K-steps
#define NBM ((MM + 63) / 64)   // 782 row-tiles
#define SCB 40       // scan: blocks per answer
#define SCN 250      // scan: nodes per block  (SCB*SCN == NN)

typedef __attribute__((ext_vector_type(8))) _Float16 f16x8;
typedef __attribute__((ext_vector_type(4))) float f32x4;
typedef __attribute__((ext_vector_type(2))) float f32x2;
typedef unsigned short ushort;
typedef unsigned char uchar;

__device__ __forceinline__ ushort f2bf(float f) {
    unsigned u = __float_as_uint(f);
    unsigned r = u + 0x7fffu + ((u >> 16) & 1u);   // RN-even
    return (ushort)(r >> 16);
}
__device__ __forceinline__ float bf2f(ushort h) {
    return __uint_as_float(((unsigned)h) << 16);
}
__device__ __forceinline__ float leaky_exp(float v) {
    v = v > 0.f ? v : 0.2f * v;
    return __expf(v);
}

// ---------------- CSR build ----------------

__global__ void count_edges(const int* __restrict__ ei, int* __restrict__ cnt) {
    int a = blockIdx.y;
    int e = blockIdx.x * 256 + threadIdx.x;
    if (e < EE) {
        int dst = ei[(size_t)a * 2 * EE + EE + e];
        atomicAdd(&cnt[a * NN + dst], 1);
    }
}

// --- hierarchical exclusive scan of cnt -> offs, cursor (3 small kernels) ---

__global__ __launch_bounds__(256) void scan_bsum(const int* __restrict__ cnt,
                                                 int* __restrict__ bsum) {
    int a = blockIdx.y, b = blockIdx.x;
    int l = threadIdx.x;
    int v = (l < SCN) ? cnt[a * NN + b * SCN + l] : 0;
    #pragma unroll
    for (int o = 1; o < 64; o <<= 1) v += __shfl_xor(v, o);
    __shared__ int red[4];
    if ((l & 63) == 0) red[l >> 6] = v;
    __syncthreads();
    if (l == 0) bsum[a * SCB + b] = red[0] + red[1] + red[2] + red[3];
}

__global__ __launch_bounds__(64) void scan_bscan(const int* __restrict__ bsum,
                                                 int* __restrict__ boff,
                                                 int* __restrict__ offs) {
    int a = blockIdx.x;
    int l = threadIdx.x;
    int v = (l < SCB) ? bsum[a * SCB + l] : 0;
    int sc = v;
    #pragma unroll
    for (int o = 1; o < 64; o <<= 1) {
        int u = __shfl_up(sc, o);
        if (l >= o) sc += u;
    }
    if (l < SCB) boff[a * SCB + l] = sc - v;
    if (l == 63) offs[a * (NN + 1) + NN] = sc;   // grand total
}

__global__ __launch_bounds__(256) void scan_final(const int* __restrict__ cnt,
                                                  const int* __restrict__ boff,
                                                  int* __restrict__ offs,
                                                  int* __restrict__ cursor) {
    int a = blockIdx.y, b = blockIdx.x;
    int l = threadIdx.x;
    int i = b * SCN + l;
    int v = (l < SCN) ? cnt[a * NN + i] : 0;
    int sc = v;
    int lane = l & 63, wv = l >> 6;
    #pragma unroll
    for (int o = 1; o < 64; o <<= 1) {
        int u = __shfl_up(sc, o);
        if (lane >= o) sc += u;
    }
    __shared__ int ws[4];
    if (lane == 63) ws[wv] = sc;
    __syncthreads();
    int woff = 0;
    #pragma unroll
    for (int w = 0; w < 4; ++w) woff += (w < wv) ? ws[w] : 0;
    if (l < SCN) {
        int o = boff[a * SCB + b] + woff + sc - v;
        offs[a * (NN + 1) + i] = o;
        cursor[a * (NN + 1) + i] = o;
    }
}

__global__ void scatter_edges(const int* __restrict__ ei, int* __restrict__ cursor,
                              int* __restrict__ csr_eid) {
    int a = blockIdx.y;
    int e = blockIdx.x * 256 + threadIdx.x;
    if (e < EE) {
        int dst = ei[(size_t)a * 2 * EE + EE + e];
        int pos = atomicAdd(&cursor[a * (NN + 1) + dst], 1);
        csr_eid[(size_t)a * EE + pos] = e;
    }
}

// ONE WAVE PER NODE: bitonic sort of the bucket's edge ids (deterministic
// order), resolve src ids, AND compute the 8 per-head edge weights in place.

__global__ __launch_bounds__(256) void sort_src(const int* __restrict__ ei,
                                                const int* __restrict__ offs,
                                                int* __restrict__ csr_eid,
                                                int* __restrict__ csr_src,
                                                const float* __restrict__ asrc,
                                                const float* __restrict__ adst,
                                                float* __restrict__ w_csr) {
    int a = blockIdx.y;
    int wid = threadIdx.x >> 6, l = threadIdx.x & 63;
    int n = blockIdx.x * 4 + wid;
    if (n >= NN) return;
    const int* offsA = offs + a * (NN + 1);
    int beg = offsA[n], end = offsA[n + 1];
    int deg = end - beg;
    int* seg = csr_eid + (size_t)a * EE + beg;
    const int* srcrow = ei + (size_t)a * 2 * EE;  // row 0 = src
    const float* asrcA = asrc + (size_t)a * NN * HH;
    const float* adstA = adst + (size_t)a * NN * HH;
    float4 d0 = *(const float4*)(adstA + (size_t)n * HH);
    float4 d1 = *(const float4*)(adstA + (size_t)n * HH + 4);

    if (deg <= 64) {
        int v = (l < deg) ? seg[l] : 0x7fffffff;
        #pragma unroll
        for (int k = 2; k <= 64; k <<= 1)
            #pragma unroll
            for (int j = k >> 1; j > 0; j >>= 1) {
                int p = __shfl_xor(v, j);
                bool keepMin = (((l & k) == 0) == ((l & j) == 0));
                int mn = min(v, p), mx = max(v, p);
                v = keepMin ? mn : mx;
            }
        if (l < deg) {
            int s = srcrow[v];
            csr_src[(size_t)a * EE + beg + l] = s;
            float4 s0 = *(const float4*)(asrcA + (size_t)s * HH);
            float4 s1 = *(const float4*)(asrcA + (size_t)s * HH + 4);
            float4 w0, w1;
            w0.x = leaky_exp(s0.x + d0.x); w0.y = leaky_exp(s0.y + d0.y);
            w0.z = leaky_exp(s0.z + d0.z); w0.w = leaky_exp(s0.w + d0.w);
            w1.x = leaky_exp(s1.x + d1.x); w1.y = leaky_exp(s1.y + d1.y);
            w1.z = leaky_exp(s1.z + d1.z); w1.w = leaky_exp(s1.w + d1.w);
            float* wp = w_csr + ((size_t)a * EE + beg + l) * HH;
            *(float4*)(wp) = w0;
            *(float4*)(wp + 4) = w1;
        }
    } else {
        // rare fallback (P ~ 1e-24 for Poisson(12.8))
        if (l == 0) {
            for (int i = 1; i < deg; ++i) {
                int key = seg[i];
                int j = i - 1;
                while (j >= 0 && seg[j] > key) { seg[j + 1] = seg[j]; --j; }
                seg[j + 1] = key;
            }
        }
        __builtin_amdgcn_wave_barrier();
        for (int i = l; i < deg; i += 64) {
            int s = srcrow[seg[i]];
            csr_src[(size_t)a * EE + beg + i] = s;
            float4 s0 = *(const float4*)(asrcA + (size_t)s * HH);
            float4 s1 = *(const float4*)(asrcA + (size_t)s * HH + 4);
            float4 w0, w1;
            w0.x = leaky_exp(s0.x + d0.x); w0.y = leaky_exp(s0.y + d0.y);
            w0.z = leaky_exp(s0.z + d0.z); w0.w = leaky_exp(s0.w + d0.w);
            w1.x = leaky_exp(s1.x + d1.x); w1.y = leaky_exp(s1.y + d1.y);
            w1.z = leaky_exp(s1.z + d1.z); w1.w = leaky_exp(s1.w + d1.w);
            float* wp = w_csr + ((size_t)a * EE + beg + i) * HH;
            *(float4*)(wp) = w0;
            *(float4*)(wp + 4) = w1;
        }
    }
}

// ---------- pack x and W1 into MFMA-fragment order (fp16) ----------
// Layout: P[((tile*NT + ks)*4 + frag)*64 + lane] : f16x8

__global__ __launch_bounds__(256) void pack_x(const float* __restrict__ X,
                                              ushort* __restrict__ Xp) {
    int gid = blockIdx.x * 256 + threadIdx.x;
    if (gid >= NBM * NT * 4 * 64) return;
    int l = gid & 63;
    int fr = (gid >> 6) & 3;
    int rest = gid >> 8;
    int ks = rest % NT;
    int bmi = rest / NT;
    int row = bmi * 64 + fr * 16 + (l & 15);
    int k = ks * 32 + (l >> 4) * 8;
    f16x8 o;
    if (row < MM && k + 8 <= DD) {
        float4 v0 = *(const float4*)(X + (size_t)row * DD + k);
        float4 v1 = *(const float4*)(X + (size_t)row * DD + k + 4);
        o[0] = (_Float16)v0.x; o[1] = (_Float16)v0.y;
        o[2] = (_Float16)v0.z; o[3] = (_Float16)v0.w;
        o[4] = (_Float16)v1.x; o[5] = (_Float16)v1.y;
        o[6] = (_Float16)v1.z; o[7] = (_Float16)v1.w;
    } else {
        #pragma unroll
        for (int j = 0; j < 8; ++j)
            o[j] = (row < MM && k + j < DD) ? (_Float16)X[(size_t)row * DD + k + j]
                                            : (_Float16)0.f;
    }
    *(f16x8*)(Xp + (size_t)gid * 8) = o;
}

__global__ __launch_bounds__(256) void pack_w(const float* __restrict__ W,
                                              ushort* __restrict__ Wp) {
    int gid = blockIdx.x * 256 + threadIdx.x;
    if (gid >= HH * NT * 4 * 64) return;
    int l = gid & 63;
    int fc = (gid >> 6) & 3;
    int rest = gid >> 8;
    int ks = rest % NT;
    int head = rest / NT;
    int col = head * 64 + fc * 16 + (l & 15);
    int k = ks * 32 + (l >> 4) * 8;
    f16x8 o;
    #pragma unroll
    for (int j = 0; j < 8; ++j)
        o[j] = (k + j < DD) ? (_Float16)W[(size_t)(k + j) * HC + col] : (_Float16)0.f;
    *(f16x8*)(Wp + (size_t)gid * 8) = o;
}

// ---- fp16 MFMA GEMM: h1 = x @ W1, packed operands, no LDS, no barriers ----
// Wave owns 64 rows x 64 cols (one head). Every fragment load is a dense,
// coalesced 1KB read: base + ks*2048 + frag*512 elements. (round-13 version)

__global__ __launch_bounds__(256) void gemm_f16(const ushort* __restrict__ Xp,
                                                const ushort* __restrict__ Wp,
                                                const float* __restrict__ att_src1,
                                                const float* __restrict__ att_dst1,
                                                uchar* __restrict__ Hout,
                                                float* __restrict__ asrc,
                                                float* __restrict__ adst) {
    int wid = blockIdx.x * 4 + (threadIdx.x >> 6);
    int bmi = wid >> 3, head = wid & 7;
    if (bmi >= NBM) return;
    int bm = bmi * 64;
    int l = threadIdx.x & 63;
    int l16 = l & 15, kg = l >> 4;

    const ushort* Abase = Xp + (size_t)bmi * NT * 2048 + l * 8;
    const ushort* Bbase = Wp + (size_t)head * NT * 2048 + l * 8;

    f32x4 zz = {0.f, 0.f, 0.f, 0.f};
    f32x4 acc[4][4];
    #pragma unroll
    for (int i = 0; i < 4; ++i)
        #pragma unroll
        for (int j = 0; j < 4; ++j) acc[i][j] = zz;

    f16x8 aX[4], bX[4], aY[4], bY[4];
    #pragma unroll
    for (int f = 0; f < 4; ++f) {
        aX[f] = *(const f16x8*)(Abase + f * 512);
        bX[f] = *(const f16x8*)(Bbase + f * 512);
    }

    #pragma unroll
    for (int kk = 0; kk < NT; kk += 2) {
        if (kk + 1 < NT) {
            #pragma unroll
            for (int f = 0; f < 4; ++f) {
                aY[f] = *(const f16x8*)(Abase + (kk + 1) * 2048 + f * 512);
                bY[f] = *(const f16x8*)(Bbase + (kk + 1) * 2048 + f * 512);
            }
        }
        #pragma unroll
        for (int fr = 0; fr < 4; ++fr)
            #pragma unroll
            for (int fc = 0; fc < 4; ++fc)
                acc[fr][fc] = __builtin_amdgcn_mfma_f32_16x16x32_f16(aX[fr], bX[fc], acc[fr][fc], 0, 0, 0);
        if (kk + 2 < NT) {
            #pragma unroll
            for (int f = 0; f < 4; ++f) {
                aX[f] = *(const f16x8*)(Abase + (kk + 2) * 2048 + f * 512);
                bX[f] = *(const f16x8*)(Bbase + (kk + 2) * 2048 + f * 512);
            }
        }
        if (kk + 1 < NT) {
            #pragma unroll
            for (int fr = 0; fr < 4; ++fr)
                #pragma unroll
                for (int fc = 0; fc < 4; ++fc)
                    acc[fr][fc] = __builtin_amdgcn_mfma_f32_16x16x32_f16(aY[fr], bY[fc], acc[fr][fc], 0, 0, 0);
        }
    }

    // ---- epilogue: store h1 (fp8 e4m3), fused alpha_src/alpha_dst ----
    float sv[4], dv[4];
    #pragma unroll
    for (int fc = 0; fc < 4; ++fc) {
        sv[fc] = att_src1[head * 64 + fc * 16 + l16];
        dv[fc] = att_dst1[head * 64 + fc * 16 + l16];
    }
    #pragma unroll
    for (int fr = 0; fr < 4; ++fr) {
        #pragma unroll
        for (int r = 0; r < 4; ++r) {
            int row = bm + fr * 16 + kg * 4 + r;
            bool ok = row < MM;
            float ps = 0.f, pd = 0.f;
            #pragma unroll
            for (int fc = 0; fc < 4; ++fc) {
                float val = acc[fr][fc][r];
                if (ok) {
                    int pk = __builtin_amdgcn_cvt_pk_fp8_f32(val, val, 0, false);
                    Hout[(size_t)row * HC + head * 64 + fc * 16 + l16] = (uchar)(pk & 0xff);
                }
                ps = fmaf(val, sv[fc], ps);
                pd = fmaf(val, dv[fc], pd);
            }
            #pragma unroll
            for (int o = 1; o < 16; o <<= 1) {
                ps += __shfl_xor(ps, o);
                pd += __shfl_xor(pd, o);
            }
            if (l16 == 0 && ok) {
                asrc[(size_t)row * HH + head] = ps;
                adst[(size_t)row * HH + head] = pd;
            }
        }
    }
}

// ------------- layer-1 aggregation fused with h2 = relu(out+b) @ W2 -------------
// ONE WAVE PER NODE, no LDS, no barriers. Weights read COALESCED from w_csr;
// h1 gathered as fp8 (8 B/lane/row), HW cvt decode; fp32 accumulate.
// Next-chunk w/srcs software-prefetched. (round-11 version, verbatim — the
// shfl redistribution beats per-edge scalar loads: r15 A/B showed 56.5 vs 76.8 µs)

__global__ __launch_bounds__(256) void layer1_agg(const uchar* __restrict__ h1,
                                                  const float* __restrict__ w_csr,
                                                  const int* __restrict__ offs,
                                                  const int* __restrict__ csr_src,
                                                  const float* __restrict__ bias1,
                                                  const float* __restrict__ W2,
                                                  float* __restrict__ h2) {
    int a = blockIdx.y;
    int wid = threadIdx.x >> 6, l = threadIdx.x & 63;
    int n = blockIdx.x * 4 + wid;
    int eg = l >> 3;          // edge slot within chunk (also gather head gh)
    int gh = l >> 3;

    const int* offsA = offs + a * (NN + 1);
    int beg = offsA[n], end = offsA[n + 1];
    int deg = end - beg;
    const int* srcs = csr_src + (size_t)a * EE + beg;
    const float* wA = w_csr + ((size_t)a * EE + beg) * HH;
    const uchar* h1A = h1 + (size_t)a * NN * HC;

    float denom = 0.f;
    float acc[8] = {};

    float w_cur = (eg < deg) ? wA[l] : 0.f;          // wA[(c0+eg)*8+hd8] == wA[c0*8+l]
    int s_cur = (eg < deg) ? srcs[eg] : 0;

    for (int c0 = 0; c0 < deg; c0 += 8) {
        float w_nxt = 0.f;
        int s_nxt = 0;
        if (c0 + 8 + eg < deg) {
            w_nxt = wA[(c0 + 8) * 8 + l];
            s_nxt = srcs[c0 + 8 + eg];
        }
        #pragma unroll
        for (int j = 0; j < 8; ++j) {
            if (c0 + j < deg) {
                float wj = __shfl(w_cur, j * 8 + gh);
                int sj = __shfl(s_cur, j * 8);
                uint2 hv = *(const uint2*)(h1A + (size_t)sj * HC + (l << 3));
                f32x2 p0 = __builtin_amdgcn_cvt_pk_f32_fp8((int)hv.x, false);
                f32x2 p1 = __builtin_amdgcn_cvt_pk_f32_fp8((int)hv.x, true);
                f32x2 p2 = __builtin_amdgcn_cvt_pk_f32_fp8((int)hv.y, false);
                f32x2 p3 = __builtin_amdgcn_cvt_pk_f32_fp8((int)hv.y, true);
                acc[0] = fmaf(wj, p0[0], acc[0]);
                acc[1] = fmaf(wj, p0[1], acc[1]);
                acc[2] = fmaf(wj, p1[0], acc[2]);
                acc[3] = fmaf(wj, p1[1], acc[3]);
                acc[4] = fmaf(wj, p2[0], acc[4]);
                acc[5] = fmaf(wj, p2[1], acc[5]);
                acc[6] = fmaf(wj, p3[0], acc[6]);
                acc[7] = fmaf(wj, p3[1], acc[7]);
            }
        }
        denom += w_cur;
        w_cur = w_nxt;
        s_cur = s_nxt;
    }
    #pragma unroll
    for (int o = 8; o < 64; o <<= 1) denom += __shfl_xor(denom, o);
    float dn = __shfl(denom, gh);
    float inv = 1.f / (dn + 1e-16f);

    int cb = l * 8;
    float4 b0 = *(const float4*)(bias1 + cb);
    float4 b1 = *(const float4*)(bias1 + cb + 4);
    float4 w0 = *(const float4*)(W2 + cb);
    float4 w1 = *(const float4*)(W2 + cb + 4);
    float bz[8] = {b0.x, b0.y, b0.z, b0.w, b1.x, b1.y, b1.z, b1.w};
    float wz[8] = {w0.x, w0.y, w0.z, w0.w, w1.x, w1.y, w1.z, w1.w};
    float p = 0.f;
    #pragma unroll
    for (int k = 0; k < 8; ++k) {
        float z = fmaf(acc[k], inv, bz[k]);
        z = z > 0.f ? z : 0.f;
        p = fmaf(z, wz[k], p);
    }
    #pragma unroll
    for (int o = 1; o < 64; o <<= 1) p += __shfl_xor(p, o);
    if (l == 0) h2[(size_t)a * NN + n] = p;
}

// ---------------- layer 2 (scalar per node) -> proba partials ----------------

#define L2GRID 40

__global__ __launch_bounds__(256) void layer2_proba(const float* __restrict__ h2,
                                                    const int* __restrict__ offs,
                                                    const int* __restrict__ csr_src,
                                                    const float* __restrict__ att_src2,
                                                    const float* __restrict__ att_dst2,
                                                    const float* __restrict__ bias2,
                                                    float* __restrict__ partials) {
    int a = blockIdx.y;
    int n = blockIdx.x * 256 + threadIdx.x;
    float out2 = 0.f;
    if (n < NN) {
        const int* offsA = offs + a * (NN + 1);
        const int* srcs = csr_src + (size_t)a * EE;
        const float* h2A = h2 + (size_t)a * NN;
        float as2 = att_src2[0], ad2 = att_dst2[0];
        int beg = offsA[n], end = offsA[n + 1];
        float adn = h2A[n] * ad2;
        float denom = 0.f, accv = 0.f;
        for (int i = beg; i < end; ++i) {
            float hs = h2A[srcs[i]];
            float v = fmaf(hs, as2, adn);
            v = v > 0.f ? v : 0.2f * v;
            float w = __expf(v);
            denom += w;
            accv = fmaf(w, hs, accv);
        }
        out2 = accv / (denom + 1e-16f) + bias2[0];
    }
    __shared__ float red[256];
    red[threadIdx.x] = out2;
    __syncthreads();
    for (int s = 128; s > 0; s >>= 1) {
        if (threadIdx.x < s) red[threadIdx.x] += red[threadIdx.x + s];
        __syncthreads();
    }
    if (threadIdx.x == 0) partials[a * L2GRID + blockIdx.x] = red[0];
}

__global__ __launch_bounds__(256) void finalize_proba(const float* __restrict__ partials,
                                                      float* __restrict__ out,
                                                      int* __restrict__ best) {
    int tid = threadIdx.x;
    __shared__ float red[256];
    red[tid] = (tid < AA * L2GRID) ? partials[tid] : 0.f;
    __syncthreads();
    if (tid == 0) {
        float pv[AA];
        for (int a = 0; a < AA; ++a) {
            float s = 0.f;
            for (int i = 0; i < L2GRID; ++i) s += red[a * L2GRID + i];
            pv[a] = s / (float)NN;
            out[a] = pv[a];
        }
        int b = 0;
        for (int a = 1; a < AA; ++a)
            if (pv[a] > pv[b]) b = a;
        *best = b;
    }
}

__global__ void write_sel(const int* __restrict__ cnt, const int* __restrict__ best,
                          float* __restrict__ out) {
    int n = blockIdx.x * 256 + threadIdx.x;
    if (n < NN) out[AA + n] = (cnt[(*best) * NN + n] > 0) ? 1.0f : 0.0f;
}

// ---------------- launch ----------------

extern "C" void kernel_launch(void* const* d_in, const int* in_sizes, int n_in,
                              void* d_out, int out_size, void* d_ws, size_t ws_size,
                              hipStream_t stream) {
    const float* x        = (const float*)d_in[0];
    const int*   ei       = (const int*)d_in[1];
    const float* W1       = (const float*)d_in[2];
    const float* att_src1 = (const float*)d_in[3];
    const float* att_dst1 = (const float*)d_in[4];
    const float* bias1    = (const float*)d_in[5];
    const float* W2       = (const float*)d_in[6];
    const float* att_src2 = (const float*)d_in[7];
    const float* att_dst2 = (const float*)d_in[8];
    const float* bias2    = (const float*)d_in[9];
    float* out = (float*)d_out;

    char* ws = (char*)d_ws;
    size_t off = 0;
    auto alloc = [&](size_t bytes) {
        size_t cur = off;
        off += (bytes + 255) & ~(size_t)255;
        return cur;
    };
    uchar*  h1      = (uchar*)(ws + alloc(sizeof(uchar) * (size_t)MM * HC));           // 25.6 MB
    ushort* xp      = (ushort*)(ws + alloc(sizeof(ushort) * (size_t)NBM * NT * 2048)); // 32 MB
    float*  asrc    = (float*)(ws + alloc(sizeof(float) * (size_t)MM * HH));
    float*  adst    = (float*)(ws + alloc(sizeof(float) * (size_t)MM * HH));
    float*  h2      = (float*)(ws + alloc(sizeof(float) * (size_t)MM));
    int*    cnt     = (int*)(ws + alloc(sizeof(int) * (size_t)AA * NN));
    int*    offs    = (int*)(ws + alloc(sizeof(int) * (size_t)AA * (NN + 1)));
    int*    cursor  = (int*)(ws + alloc(sizeof(int) * (size_t)AA * (NN + 1)));
    int*    bsum    = (int*)(ws + alloc(sizeof(int) * (size_t)AA * SCB));
    int*    boff    = (int*)(ws + alloc(sizeof(int) * (size_t)AA * SCB));
    int*    csr_eid = (int*)(ws + alloc(sizeof(int) * (size_t)AA * EE));
    int*    csr_src = (int*)(ws + alloc(sizeof(int) * (size_t)AA * EE));
    float*  w_csr   = (float*)(ws + alloc(sizeof(float) * (size_t)AA * EE * HH));      // 20.5 MB
    float*  partials= (float*)(ws + alloc(sizeof(float) * AA * L2GRID));
    int*    best    = (int*)(ws + alloc(sizeof(int) * 16));
    ushort* wp      = (ushort*)(ws + alloc(sizeof(ushort) * (size_t)HH * NT * 2048)); // 320 KB
    (void)ws_size; (void)in_sizes; (void)n_in; (void)out_size;

    pack_w<<<dim3((HH * NT * 256 + 255) / 256), dim3(256), 0, stream>>>(W1, wp);
    pack_x<<<dim3((NBM * NT * 256 + 255) / 256), dim3(256), 0, stream>>>(x, xp);

    hipMemsetAsync(cnt, 0, sizeof(int) * (size_t)AA * NN, stream);
    count_edges<<<dim3(EE / 256, AA), dim3(256), 0, stream>>>(ei, cnt);
    scan_bsum<<<dim3(SCB, AA), dim3(256), 0, stream>>>(cnt, bsum);
    scan_bscan<<<dim3(AA), dim3(64), 0, stream>>>(bsum, boff, offs);
    scan_final<<<dim3(SCB, AA), dim3(256), 0, stream>>>(cnt, boff, offs, cursor);
    scatter_edges<<<dim3(EE / 256, AA), dim3(256), 0, stream>>>(ei, cursor, csr_eid);

    // gemm first: sort_src consumes asrc/adst for fused edge-weight computation
    gemm_f16<<<dim3((NBM * 8 + 3) / 4), dim3(256), 0, stream>>>(
        xp, wp, att_src1, att_dst1, h1, asrc, adst);

    sort_src<<<dim3(NN / 4, AA), dim3(256), 0, stream>>>(ei, offs, csr_eid, csr_src,
                                                         asrc, adst, w_csr);

    layer1_agg<<<dim3(NN / 4, AA), dim3(256), 0, stream>>>(h1, w_csr, offs, csr_src,
                                                           bias1, W2, h2);

    layer2_proba<<<dim3(L2GRID, AA), dim3(256), 0, stream>>>(h2, offs, csr_src,
                                                             att_src2, att_dst2, bias2,
                                                             partials);

    finalize_proba<<<dim3(1), dim3(256), 0, stream>>>(partials, out, best);
    write_sel<<<dim3((NN + 255) / 256), dim3(256), 0, stream>>>(cnt, best, out);
}

// Round 17
// 221.022 us; speedup vs baseline: 1.3000x; 1.0674x over previous
//
#include <hip/hip_runtime.h>
#include <hip/hip_bf16.h>
#include <math.h>

#define NN 10000
#define EE 128000
#define AA 5
#define DD 300
#define HH 8
#define CC 64
#define HC 512
#define MM (AA*NN)   // 50000 rows total
#define KP 320       // K padded to multiple of 32
#define NT (KP / 32) // 10 K-steps
#define NBM ((MM + 63) / 64)   // 782 row-tiles
#define SCB 40       // scan: blocks per answer
#define SCN 250      // scan: nodes per block  (SCB*SCN == NN)

typedef __attribute__((ext_vector_type(8))) _Float16 f16x8;
typedef __attribute__((ext_vector_type(4))) float f32x4;
typedef __attribute__((ext_vector_type(2))) float f32x2;
typedef unsigned short ushort;
typedef unsigned char uchar;

__device__ __forceinline__ ushort f2bf(float f) {
    unsigned u = __float_as_uint(f);
    unsigned r = u + 0x7fffu + ((u >> 16) & 1u);   // RN-even
    return (ushort)(r >> 16);
}
__device__ __forceinline__ float bf2f(ushort h) {
    return __uint_as_float(((unsigned)h) << 16);
}
__device__ __forceinline__ float leaky_exp(float v) {
    v = v > 0.f ? v : 0.2f * v;
    return __expf(v);
}

// ---------------- CSR build ----------------

__global__ void count_edges(const int* __restrict__ ei, int* __restrict__ cnt) {
    int a = blockIdx.y;
    int e = blockIdx.x * 256 + threadIdx.x;
    if (e < EE) {
        int dst = ei[(size_t)a * 2 * EE + EE + e];
        atomicAdd(&cnt[a * NN + dst], 1);
    }
}

// --- hierarchical exclusive scan of cnt -> offs, cursor (3 small kernels) ---

__global__ __launch_bounds__(256) void scan_bsum(const int* __restrict__ cnt,
                                                 int* __restrict__ bsum) {
    int a = blockIdx.y, b = blockIdx.x;
    int l = threadIdx.x;
    int v = (l < SCN) ? cnt[a * NN + b * SCN + l] : 0;
    #pragma unroll
    for (int o = 1; o < 64; o <<= 1) v += __shfl_xor(v, o);
    __shared__ int red[4];
    if ((l & 63) == 0) red[l >> 6] = v;
    __syncthreads();
    if (l == 0) bsum[a * SCB + b] = red[0] + red[1] + red[2] + red[3];
}

__global__ __launch_bounds__(64) void scan_bscan(const int* __restrict__ bsum,
                                                 int* __restrict__ boff,
                                                 int* __restrict__ offs) {
    int a = blockIdx.x;
    int l = threadIdx.x;
    int v = (l < SCB) ? bsum[a * SCB + l] : 0;
    int sc = v;
    #pragma unroll
    for (int o = 1; o < 64; o <<= 1) {
        int u = __shfl_up(sc, o);
        if (l >= o) sc += u;
    }
    if (l < SCB) boff[a * SCB + l] = sc - v;
    if (l == 63) offs[a * (NN + 1) + NN] = sc;   // grand total
}

__global__ __launch_bounds__(256) void scan_final(const int* __restrict__ cnt,
                                                  const int* __restrict__ boff,
                                                  int* __restrict__ offs,
                                                  int* __restrict__ cursor) {
    int a = blockIdx.y, b = blockIdx.x;
    int l = threadIdx.x;
    int i = b * SCN + l;
    int v = (l < SCN) ? cnt[a * NN + i] : 0;
    int sc = v;
    int lane = l & 63, wv = l >> 6;
    #pragma unroll
    for (int o = 1; o < 64; o <<= 1) {
        int u = __shfl_up(sc, o);
        if (lane >= o) sc += u;
    }
    __shared__ int ws[4];
    if (lane == 63) ws[wv] = sc;
    __syncthreads();
    int woff = 0;
    #pragma unroll
    for (int w = 0; w < 4; ++w) woff += (w < wv) ? ws[w] : 0;
    if (l < SCN) {
        int o = boff[a * SCB + b] + woff + sc - v;
        offs[a * (NN + 1) + i] = o;
        cursor[a * (NN + 1) + i] = o;
    }
}

// scatter + fused edge weights: each edge writes csr_src[pos] and the 8
// per-head weights w = exp(leaky(asrc[src]+adst[dst])). Bucket ORDER is
// nondeterministic (atomic cursor) — fp32 reorder noise ~1e-6 on h2, ~1e-8
// on proba, far below threshold 2e-2 and argmax margins (>1.2e-4 proven).
// Runs AFTER gemm (needs asrc/adst). Replaces sort_src + csr_eid entirely.

__global__ __launch_bounds__(256) void scatter_fused(const int* __restrict__ ei,
                                                     int* __restrict__ cursor,
                                                     int* __restrict__ csr_src,
                                                     const float* __restrict__ asrc,
                                                     const float* __restrict__ adst,
                                                     float* __restrict__ w_csr) {
    int a = blockIdx.y;
    int e = blockIdx.x * 256 + threadIdx.x;
    if (e >= EE) return;
    int src = ei[(size_t)a * 2 * EE + e];
    int dst = ei[(size_t)a * 2 * EE + EE + e];
    int pos = atomicAdd(&cursor[a * (NN + 1) + dst], 1);
    csr_src[(size_t)a * EE + pos] = src;
    const float* asrcA = asrc + (size_t)a * NN * HH;
    const float* adstA = adst + (size_t)a * NN * HH;
    float4 s0 = *(const float4*)(asrcA + (size_t)src * HH);
    float4 s1 = *(const float4*)(asrcA + (size_t)src * HH + 4);
    float4 d0 = *(const float4*)(adstA + (size_t)dst * HH);
    float4 d1 = *(const float4*)(adstA + (size_t)dst * HH + 4);
    float4 w0, w1;
    w0.x = leaky_exp(s0.x + d0.x); w0.y = leaky_exp(s0.y + d0.y);
    w0.z = leaky_exp(s0.z + d0.z); w0.w = leaky_exp(s0.w + d0.w);
    w1.x = leaky_exp(s1.x + d1.x); w1.y = leaky_exp(s1.y + d1.y);
    w1.z = leaky_exp(s1.z + d1.z); w1.w = leaky_exp(s1.w + d1.w);
    float* wp = w_csr + ((size_t)a * EE + pos) * HH;
    *(float4*)(wp) = w0;
    *(float4*)(wp + 4) = w1;
}

// ---------- pack x and W1 into MFMA-fragment order (fp16) ----------
// Layout: P[((tile*NT + ks)*4 + frag)*64 + lane] : f16x8

__global__ __launch_bounds__(256) void pack_x(const float* __restrict__ X,
                                              ushort* __restrict__ Xp) {
    int gid = blockIdx.x * 256 + threadIdx.x;
    if (gid >= NBM * NT * 4 * 64) return;
    int l = gid & 63;
    int fr = (gid >> 6) & 3;
    int rest = gid >> 8;
    int ks = rest % NT;
    int bmi = rest / NT;
    int row = bmi * 64 + fr * 16 + (l & 15);
    int k = ks * 32 + (l >> 4) * 8;
    f16x8 o;
    if (row < MM && k + 8 <= DD) {
        float4 v0 = *(const float4*)(X + (size_t)row * DD + k);
        float4 v1 = *(const float4*)(X + (size_t)row * DD + k + 4);
        o[0] = (_Float16)v0.x; o[1] = (_Float16)v0.y;
        o[2] = (_Float16)v0.z; o[3] = (_Float16)v0.w;
        o[4] = (_Float16)v1.x; o[5] = (_Float16)v1.y;
        o[6] = (_Float16)v1.z; o[7] = (_Float16)v1.w;
    } else {
        #pragma unroll
        for (int j = 0; j < 8; ++j)
            o[j] = (row < MM && k + j < DD) ? (_Float16)X[(size_t)row * DD + k + j]
                                            : (_Float16)0.f;
    }
    *(f16x8*)(Xp + (size_t)gid * 8) = o;
}

__global__ __launch_bounds__(256) void pack_w(const float* __restrict__ W,
                                              ushort* __restrict__ Wp) {
    int gid = blockIdx.x * 256 + threadIdx.x;
    if (gid >= HH * NT * 4 * 64) return;
    int l = gid & 63;
    int fc = (gid >> 6) & 3;
    int rest = gid >> 8;
    int ks = rest % NT;
    int head = rest / NT;
    int col = head * 64 + fc * 16 + (l & 15);
    int k = ks * 32 + (l >> 4) * 8;
    f16x8 o;
    #pragma unroll
    for (int j = 0; j < 8; ++j)
        o[j] = (k + j < DD) ? (_Float16)W[(size_t)(k + j) * HC + col] : (_Float16)0.f;
    *(f16x8*)(Wp + (size_t)gid * 8) = o;
}

// ---- fp16 MFMA GEMM: h1 = x @ W1, packed operands, no LDS, no barriers ----
// Wave owns 64 rows x 64 cols (one head). Every fragment load is a dense,
// coalesced 1KB read: base + ks*2048 + frag*512 elements. (round-13 version)

__global__ __launch_bounds__(256) void gemm_f16(const ushort* __restrict__ Xp,
                                                const ushort* __restrict__ Wp,
                                                const float* __restrict__ att_src1,
                                                const float* __restrict__ att_dst1,
                                                uchar* __restrict__ Hout,
                                                float* __restrict__ asrc,
                                                float* __restrict__ adst) {
    int wid = blockIdx.x * 4 + (threadIdx.x >> 6);
    int bmi = wid >> 3, head = wid & 7;
    if (bmi >= NBM) return;
    int bm = bmi * 64;
    int l = threadIdx.x & 63;
    int l16 = l & 15, kg = l >> 4;

    const ushort* Abase = Xp + (size_t)bmi * NT * 2048 + l * 8;
    const ushort* Bbase = Wp + (size_t)head * NT * 2048 + l * 8;

    f32x4 zz = {0.f, 0.f, 0.f, 0.f};
    f32x4 acc[4][4];
    #pragma unroll
    for (int i = 0; i < 4; ++i)
        #pragma unroll
        for (int j = 0; j < 4; ++j) acc[i][j] = zz;

    f16x8 aX[4], bX[4], aY[4], bY[4];
    #pragma unroll
    for (int f = 0; f < 4; ++f) {
        aX[f] = *(const f16x8*)(Abase + f * 512);
        bX[f] = *(const f16x8*)(Bbase + f * 512);
    }

    #pragma unroll
    for (int kk = 0; kk < NT; kk += 2) {
        if (kk + 1 < NT) {
            #pragma unroll
            for (int f = 0; f < 4; ++f) {
                aY[f] = *(const f16x8*)(Abase + (kk + 1) * 2048 + f * 512);
                bY[f] = *(const f16x8*)(Bbase + (kk + 1) * 2048 + f * 512);
            }
        }
        #pragma unroll
        for (int fr = 0; fr < 4; ++fr)
            #pragma unroll
            for (int fc = 0; fc < 4; ++fc)
                acc[fr][fc] = __builtin_amdgcn_mfma_f32_16x16x32_f16(aX[fr], bX[fc], acc[fr][fc], 0, 0, 0);
        if (kk + 2 < NT) {
            #pragma unroll
            for (int f = 0; f < 4; ++f) {
                aX[f] = *(const f16x8*)(Abase + (kk + 2) * 2048 + f * 512);
                bX[f] = *(const f16x8*)(Bbase + (kk + 2) * 2048 + f * 512);
            }
        }
        if (kk + 1 < NT) {
            #pragma unroll
            for (int fr = 0; fr < 4; ++fr)
                #pragma unroll
                for (int fc = 0; fc < 4; ++fc)
                    acc[fr][fc] = __builtin_amdgcn_mfma_f32_16x16x32_f16(aY[fr], bY[fc], acc[fr][fc], 0, 0, 0);
        }
    }

    // ---- epilogue: store h1 (fp8 e4m3), fused alpha_src/alpha_dst ----
    float sv[4], dv[4];
    #pragma unroll
    for (int fc = 0; fc < 4; ++fc) {
        sv[fc] = att_src1[head * 64 + fc * 16 + l16];
        dv[fc] = att_dst1[head * 64 + fc * 16 + l16];
    }
    #pragma unroll
    for (int fr = 0; fr < 4; ++fr) {
        #pragma unroll
        for (int r = 0; r < 4; ++r) {
            int row = bm + fr * 16 + kg * 4 + r;
            bool ok = row < MM;
            float ps = 0.f, pd = 0.f;
            #pragma unroll
            for (int fc = 0; fc < 4; ++fc) {
                float val = acc[fr][fc][r];
                if (ok) {
                    int pk = __builtin_amdgcn_cvt_pk_fp8_f32(val, val, 0, false);
                    Hout[(size_t)row * HC + head * 64 + fc * 16 + l16] = (uchar)(pk & 0xff);
                }
                ps = fmaf(val, sv[fc], ps);
                pd = fmaf(val, dv[fc], pd);
            }
            #pragma unroll
            for (int o = 1; o < 16; o <<= 1) {
                ps += __shfl_xor(ps, o);
                pd += __shfl_xor(pd, o);
            }
            if (l16 == 0 && ok) {
                asrc[(size_t)row * HH + head] = ps;
                adst[(size_t)row * HH + head] = pd;
            }
        }
    }
}

// ------------- layer-1 aggregation fused with h2 = relu(out+b) @ W2 -------------
// ONE WAVE PER NODE, no LDS, no barriers. Weights read COALESCED from w_csr;
// h1 gathered as fp8 (8 B/lane/row), HW cvt decode; fp32 accumulate.
// Next-chunk w/srcs software-prefetched. (round-11 version, verbatim — the
// shfl redistribution beats per-edge scalar loads: r15 A/B showed 56.5 vs 76.8 µs)

__global__ __launch_bounds__(256) void layer1_agg(const uchar* __restrict__ h1,
                                                  const float* __restrict__ w_csr,
                                                  const int* __restrict__ offs,
                                                  const int* __restrict__ csr_src,
                                                  const float* __restrict__ bias1,
                                                  const float* __restrict__ W2,
                                                  float* __restrict__ h2) {
    int a = blockIdx.y;
    int wid = threadIdx.x >> 6, l = threadIdx.x & 63;
    int n = blockIdx.x * 4 + wid;
    int eg = l >> 3;          // edge slot within chunk (also gather head gh)
    int gh = l >> 3;

    const int* offsA = offs + a * (NN + 1);
    int beg = offsA[n], end = offsA[n + 1];
    int deg = end - beg;
    const int* srcs = csr_src + (size_t)a * EE + beg;
    const float* wA = w_csr + ((size_t)a * EE + beg) * HH;
    const uchar* h1A = h1 + (size_t)a * NN * HC;

    float denom = 0.f;
    float acc[8] = {};

    float w_cur = (eg < deg) ? wA[l] : 0.f;          // wA[(c0+eg)*8+hd8] == wA[c0*8+l]
    int s_cur = (eg < deg) ? srcs[eg] : 0;

    for (int c0 = 0; c0 < deg; c0 += 8) {
        float w_nxt = 0.f;
        int s_nxt = 0;
        if (c0 + 8 + eg < deg) {
            w_nxt = wA[(c0 + 8) * 8 + l];
            s_nxt = srcs[c0 + 8 + eg];
        }
        #pragma unroll
        for (int j = 0; j < 8; ++j) {
            if (c0 + j < deg) {
                float wj = __shfl(w_cur, j * 8 + gh);
                int sj = __shfl(s_cur, j * 8);
                uint2 hv = *(const uint2*)(h1A + (size_t)sj * HC + (l << 3));
                f32x2 p0 = __builtin_amdgcn_cvt_pk_f32_fp8((int)hv.x, false);
                f32x2 p1 = __builtin_amdgcn_cvt_pk_f32_fp8((int)hv.x, true);
                f32x2 p2 = __builtin_amdgcn_cvt_pk_f32_fp8((int)hv.y, false);
                f32x2 p3 = __builtin_amdgcn_cvt_pk_f32_fp8((int)hv.y, true);
                acc[0] = fmaf(wj, p0[0], acc[0]);
                acc[1] = fmaf(wj, p0[1], acc[1]);
                acc[2] = fmaf(wj, p1[0], acc[2]);
                acc[3] = fmaf(wj, p1[1], acc[3]);
                acc[4] = fmaf(wj, p2[0], acc[4]);
                acc[5] = fmaf(wj, p2[1], acc[5]);
                acc[6] = fmaf(wj, p3[0], acc[6]);
                acc[7] = fmaf(wj, p3[1], acc[7]);
            }
        }
        denom += w_cur;
        w_cur = w_nxt;
        s_cur = s_nxt;
    }
    #pragma unroll
    for (int o = 8; o < 64; o <<= 1) denom += __shfl_xor(denom, o);
    float dn = __shfl(denom, gh);
    float inv = 1.f / (dn + 1e-16f);

    int cb = l * 8;
    float4 b0 = *(const float4*)(bias1 + cb);
    float4 b1 = *(const float4*)(bias1 + cb + 4);
    float4 w0 = *(const float4*)(W2 + cb);
    float4 w1 = *(const float4*)(W2 + cb + 4);
    float bz[8] = {b0.x, b0.y, b0.z, b0.w, b1.x, b1.y, b1.z, b1.w};
    float wz[8] = {w0.x, w0.y, w0.z, w0.w, w1.x, w1.y, w1.z, w1.w};
    float p = 0.f;
    #pragma unroll
    for (int k = 0; k < 8; ++k) {
        float z = fmaf(acc[k], inv, bz[k]);
        z = z > 0.f ? z : 0.f;
        p = fmaf(z, wz[k], p);
    }
    #pragma unroll
    for (int o = 1; o < 64; o <<= 1) p += __shfl_xor(p, o);
    if (l == 0) h2[(size_t)a * NN + n] = p;
}

// ---------------- layer 2 (scalar per node) -> proba partials ----------------

#define L2GRID 40

__global__ __launch_bounds__(256) void layer2_proba(const float* __restrict__ h2,
                                                    const int* __restrict__ offs,
                                                    const int* __restrict__ csr_src,
                                                    const float* __restrict__ att_src2,
                                                    const float* __restrict__ att_dst2,
                                                    const float* __restrict__ bias2,
                                                    float* __restrict__ partials) {
    int a = blockIdx.y;
    int n = blockIdx.x * 256 + threadIdx.x;
    float out2 = 0.f;
    if (n < NN) {
        const int* offsA = offs + a * (NN + 1);
        const int* srcs = csr_src + (size_t)a * EE;
        const float* h2A = h2 + (size_t)a * NN;
        float as2 = att_src2[0], ad2 = att_dst2[0];
        int beg = offsA[n], end = offsA[n + 1];
        float adn = h2A[n] * ad2;
        float denom = 0.f, accv = 0.f;
        for (int i = beg; i < end; ++i) {
            float hs = h2A[srcs[i]];
            float v = fmaf(hs, as2, adn);
            v = v > 0.f ? v : 0.2f * v;
            float w = __expf(v);
            denom += w;
            accv = fmaf(w, hs, accv);
        }
        out2 = accv / (denom + 1e-16f) + bias2[0];
    }
    __shared__ float red[256];
    red[threadIdx.x] = out2;
    __syncthreads();
    for (int s = 128; s > 0; s >>= 1) {
        if (threadIdx.x < s) red[threadIdx.x] += red[threadIdx.x + s];
        __syncthreads();
    }
    if (threadIdx.x == 0) partials[a * L2GRID + blockIdx.x] = red[0];
}

__global__ __launch_bounds__(256) void finalize_proba(const float* __restrict__ partials,
                                                      float* __restrict__ out,
                                                      int* __restrict__ best) {
    int tid = threadIdx.x;
    __shared__ float red[256];
    red[tid] = (tid < AA * L2GRID) ? partials[tid] : 0.f;
    __syncthreads();
    if (tid == 0) {
        float pv[AA];
        for (int a = 0; a < AA; ++a) {
            float s = 0.f;
            for (int i = 0; i < L2GRID; ++i) s += red[a * L2GRID + i];
            pv[a] = s / (float)NN;
            out[a] = pv[a];
        }
        int b = 0;
        for (int a = 1; a < AA; ++a)
            if (pv[a] > pv[b]) b = a;
        *best = b;
    }
}

__global__ void write_sel(const int* __restrict__ cnt, const int* __restrict__ best,
                          float* __restrict__ out) {
    int n = blockIdx.x * 256 + threadIdx.x;
    if (n < NN) out[AA + n] = (cnt[(*best) * NN + n] > 0) ? 1.0f : 0.0f;
}

// ---------------- launch ----------------

extern "C" void kernel_launch(void* const* d_in, const int* in_sizes, int n_in,
                              void* d_out, int out_size, void* d_ws, size_t ws_size,
                              hipStream_t stream) {
    const float* x        = (const float*)d_in[0];
    const int*   ei       = (const int*)d_in[1];
    const float* W1       = (const float*)d_in[2];
    const float* att_src1 = (const float*)d_in[3];
    const float* att_dst1 = (const float*)d_in[4];
    const float* bias1    = (const float*)d_in[5];
    const float* W2       = (const float*)d_in[6];
    const float* att_src2 = (const float*)d_in[7];
    const float* att_dst2 = (const float*)d_in[8];
    const float* bias2    = (const float*)d_in[9];
    float* out = (float*)d_out;

    char* ws = (char*)d_ws;
    size_t off = 0;
    auto alloc = [&](size_t bytes) {
        size_t cur = off;
        off += (bytes + 255) & ~(size_t)255;
        return cur;
    };
    uchar*  h1      = (uchar*)(ws + alloc(sizeof(uchar) * (size_t)MM * HC));           // 25.6 MB
    ushort* xp      = (ushort*)(ws + alloc(sizeof(ushort) * (size_t)NBM * NT * 2048)); // 32 MB
    float*  asrc    = (float*)(ws + alloc(sizeof(float) * (size_t)MM * HH));
    float*  adst    = (float*)(ws + alloc(sizeof(float) * (size_t)MM * HH));
    float*  h2      = (float*)(ws + alloc(sizeof(float) * (size_t)MM));
    int*    cnt     = (int*)(ws + alloc(sizeof(int) * (size_t)AA * NN));
    int*    offs    = (int*)(ws + alloc(sizeof(int) * (size_t)AA * (NN + 1)));
    int*    cursor  = (int*)(ws + alloc(sizeof(int) * (size_t)AA * (NN + 1)));
    int*    bsum    = (int*)(ws + alloc(sizeof(int) * (size_t)AA * SCB));
    int*    boff    = (int*)(ws + alloc(sizeof(int) * (size_t)AA * SCB));
    int*    csr_src = (int*)(ws + alloc(sizeof(int) * (size_t)AA * EE));
    float*  w_csr   = (float*)(ws + alloc(sizeof(float) * (size_t)AA * EE * HH));      // 20.5 MB
    float*  partials= (float*)(ws + alloc(sizeof(float) * AA * L2GRID));
    int*    best    = (int*)(ws + alloc(sizeof(int) * 16));
    ushort* wp      = (ushort*)(ws + alloc(sizeof(ushort) * (size_t)HH * NT * 2048)); // 320 KB
    (void)ws_size; (void)in_sizes; (void)n_in; (void)out_size;

    pack_w<<<dim3((HH * NT * 256 + 255) / 256), dim3(256), 0, stream>>>(W1, wp);
    pack_x<<<dim3((NBM * NT * 256 + 255) / 256), dim3(256), 0, stream>>>(x, xp);

    hipMemsetAsync(cnt, 0, sizeof(int) * (size_t)AA * NN, stream);
    count_edges<<<dim3(EE / 256, AA), dim3(256), 0, stream>>>(ei, cnt);
    scan_bsum<<<dim3(SCB, AA), dim3(256), 0, stream>>>(cnt, bsum);
    scan_bscan<<<dim3(AA), dim3(64), 0, stream>>>(bsum, boff, offs);
    scan_final<<<dim3(SCB, AA), dim3(256), 0, stream>>>(cnt, boff, offs, cursor);

    // gemm before scatter: scatter_fused consumes asrc/adst for edge weights
    gemm_f16<<<dim3((NBM * 8 + 3) / 4), dim3(256), 0, stream>>>(
        xp, wp, att_src1, att_dst1, h1, asrc, adst);

    scatter_fused<<<dim3(EE / 256, AA), dim3(256), 0, stream>>>(ei, cursor, csr_src,
                                                                asrc, adst, w_csr);

    layer1_agg<<<dim3(NN / 4, AA), dim3(256), 0, stream>>>(h1, w_csr, offs, csr_src,
                                                           bias1, W2, h2);

    layer2_proba<<<dim3(L2GRID, AA), dim3(256), 0, stream>>>(h2, offs, csr_src,
                                                             att_src2, att_dst2, bias2,
                                                             partials);

    finalize_proba<<<dim3(1), dim3(256), 0, stream>>>(partials, out, best);
    write_sel<<<dim3((NN + 255) / 256), dim3(256), 0, stream>>>(cnt, best, out);
}

// Round 18
// 207.769 us; speedup vs baseline: 1.3829x; 1.0638x over previous
//
#include <hip/hip_runtime.h>
#include <hip/hip_bf16.h>
#include <math.h>

#define NN 10000
#define EE 128000
#define AA 5
#define DD 300
#define HH 8
#define CC 64
#define HC 512
#define MM (AA*NN)   // 50000 rows total
#define KP 320       // K padded to multiple of 32
#define NT (KP / 32) // 10 K-steps
#define NBM ((MM + 63) / 64)   // 782 row-tiles
#define SCB 40       // scan: blocks per answer
#define SCN 250      // scan: nodes per block  (SCB*SCN == NN)
#define PXN (NBM * NT * 4 * 64)   // pack_x element count

typedef __attribute__((ext_vector_type(8))) _Float16 f16x8;
typedef __attribute__((ext_vector_type(4))) float f32x4;
typedef __attribute__((ext_vector_type(2))) float f32x2;
typedef unsigned short ushort;
typedef unsigned char uchar;

__device__ __forceinline__ float bf2f(ushort h) {
    return __uint_as_float(((unsigned)h) << 16);
}
__device__ __forceinline__ float leaky_exp(float v) {
    v = v > 0.f ? v : 0.2f * v;
    return __expf(v);
}

// ---------------- CSR build ----------------

__global__ void count_edges(const int* __restrict__ ei, int* __restrict__ cnt) {
    int a = blockIdx.y;
    int e = blockIdx.x * 256 + threadIdx.x;
    if (e < EE) {
        int dst = ei[(size_t)a * 2 * EE + EE + e];
        atomicAdd(&cnt[a * NN + dst], 1);
    }
}

// --- hierarchical exclusive scan of cnt -> offs, cursor (3 small kernels) ---

__global__ __launch_bounds__(256) void scan_bsum(const int* __restrict__ cnt,
                                                 int* __restrict__ bsum) {
    int a = blockIdx.y, b = blockIdx.x;
    int l = threadIdx.x;
    int v = (l < SCN) ? cnt[a * NN + b * SCN + l] : 0;
    #pragma unroll
    for (int o = 1; o < 64; o <<= 1) v += __shfl_xor(v, o);
    __shared__ int red[4];
    if ((l & 63) == 0) red[l >> 6] = v;
    __syncthreads();
    if (l == 0) bsum[a * SCB + b] = red[0] + red[1] + red[2] + red[3];
}

__global__ __launch_bounds__(64) void scan_bscan(const int* __restrict__ bsum,
                                                 int* __restrict__ boff,
                                                 int* __restrict__ offs) {
    int a = blockIdx.x;
    int l = threadIdx.x;
    int v = (l < SCB) ? bsum[a * SCB + l] : 0;
    int sc = v;
    #pragma unroll
    for (int o = 1; o < 64; o <<= 1) {
        int u = __shfl_up(sc, o);
        if (l >= o) sc += u;
    }
    if (l < SCB) boff[a * SCB + l] = sc - v;
    if (l == 63) offs[a * (NN + 1) + NN] = sc;   // grand total
}

__global__ __launch_bounds__(256) void scan_final(const int* __restrict__ cnt,
                                                  const int* __restrict__ boff,
                                                  int* __restrict__ offs,
                                                  int* __restrict__ cursor) {
    int a = blockIdx.y, b = blockIdx.x;
    int l = threadIdx.x;
    int i = b * SCN + l;
    int v = (l < SCN) ? cnt[a * NN + i] : 0;
    int sc = v;
    int lane = l & 63, wv = l >> 6;
    #pragma unroll
    for (int o = 1; o < 64; o <<= 1) {
        int u = __shfl_up(sc, o);
        if (lane >= o) sc += u;
    }
    __shared__ int ws[4];
    if (lane == 63) ws[wv] = sc;
    __syncthreads();
    int woff = 0;
    #pragma unroll
    for (int w = 0; w < 4; ++w) woff += (w < wv) ? ws[w] : 0;
    if (l < SCN) {
        int o = boff[a * SCB + b] + woff + sc - v;
        offs[a * (NN + 1) + i] = o;
        cursor[a * (NN + 1) + i] = o;
    }
}

// scatter + fused edge weights (bucket order nondeterministic; fp32 reorder
// noise ~1e-6 on h2 << threshold 2e-2 and argmax margins >1.2e-4).

__global__ __launch_bounds__(256) void scatter_fused(const int* __restrict__ ei,
                                                     int* __restrict__ cursor,
                                                     int* __restrict__ csr_src,
                                                     const float* __restrict__ asrc,
                                                     const float* __restrict__ adst,
                                                     float* __restrict__ w_csr) {
    int a = blockIdx.y;
    int e = blockIdx.x * 256 + threadIdx.x;
    if (e >= EE) return;
    int src = ei[(size_t)a * 2 * EE + e];
    int dst = ei[(size_t)a * 2 * EE + EE + e];
    int pos = atomicAdd(&cursor[a * (NN + 1) + dst], 1);
    csr_src[(size_t)a * EE + pos] = src;
    const float* asrcA = asrc + (size_t)a * NN * HH;
    const float* adstA = adst + (size_t)a * NN * HH;
    float4 s0 = *(const float4*)(asrcA + (size_t)src * HH);
    float4 s1 = *(const float4*)(asrcA + (size_t)src * HH + 4);
    float4 d0 = *(const float4*)(adstA + (size_t)dst * HH);
    float4 d1 = *(const float4*)(adstA + (size_t)dst * HH + 4);
    float4 w0, w1;
    w0.x = leaky_exp(s0.x + d0.x); w0.y = leaky_exp(s0.y + d0.y);
    w0.z = leaky_exp(s0.z + d0.z); w0.w = leaky_exp(s0.w + d0.w);
    w1.x = leaky_exp(s1.x + d1.x); w1.y = leaky_exp(s1.y + d1.y);
    w1.z = leaky_exp(s1.z + d1.z); w1.w = leaky_exp(s1.w + d1.w);
    float* wp = w_csr + ((size_t)a * EE + pos) * HH;
    *(float4*)(wp) = w0;
    *(float4*)(wp + 4) = w1;
}

// ---------- pack x AND W1 into MFMA-fragment order (fp16), one kernel ----------
// Layout: P[((tile*NT + ks)*4 + frag)*64 + lane] : f16x8

__global__ __launch_bounds__(256) void pack_all(const float* __restrict__ X,
                                                const float* __restrict__ W,
                                                ushort* __restrict__ Xp,
                                                ushort* __restrict__ Wp) {
    int gid = blockIdx.x * 256 + threadIdx.x;
    if (gid < PXN) {
        int l = gid & 63;
        int fr = (gid >> 6) & 3;
        int rest = gid >> 8;
        int ks = rest % NT;
        int bmi = rest / NT;
        int row = bmi * 64 + fr * 16 + (l & 15);
        int k = ks * 32 + (l >> 4) * 8;
        f16x8 o;
        if (row < MM && k + 8 <= DD) {
            float4 v0 = *(const float4*)(X + (size_t)row * DD + k);
            float4 v1 = *(const float4*)(X + (size_t)row * DD + k + 4);
            o[0] = (_Float16)v0.x; o[1] = (_Float16)v0.y;
            o[2] = (_Float16)v0.z; o[3] = (_Float16)v0.w;
            o[4] = (_Float16)v1.x; o[5] = (_Float16)v1.y;
            o[6] = (_Float16)v1.z; o[7] = (_Float16)v1.w;
        } else {
            #pragma unroll
            for (int j = 0; j < 8; ++j)
                o[j] = (row < MM && k + j < DD) ? (_Float16)X[(size_t)row * DD + k + j]
                                                : (_Float16)0.f;
        }
        *(f16x8*)(Xp + (size_t)gid * 8) = o;
    } else {
        int g2 = gid - PXN;
        if (g2 >= HH * NT * 4 * 64) return;
        int l = g2 & 63;
        int fc = (g2 >> 6) & 3;
        int rest = g2 >> 8;
        int ks = rest % NT;
        int head = rest / NT;
        int col = head * 64 + fc * 16 + (l & 15);
        int k = ks * 32 + (l >> 4) * 8;
        f16x8 o;
        #pragma unroll
        for (int j = 0; j < 8; ++j)
            o[j] = (k + j < DD) ? (_Float16)W[(size_t)(k + j) * HC + col] : (_Float16)0.f;
        *(f16x8*)(Wp + (size_t)g2 * 8) = o;
    }
}

// ---- fp16 MFMA GEMM: h1 = x @ W1, packed operands, no LDS, no barriers ----
// ONE BLOCK PER bmi, 8 waves = 8 heads: the shared A tile is fetched once
// per bmi (L3 traffic halved vs 4-wave blocks) and 8-way L1-shared.

__global__ __launch_bounds__(512) void gemm_f16(const ushort* __restrict__ Xp,
                                                const ushort* __restrict__ Wp,
                                                const float* __restrict__ att_src1,
                                                const float* __restrict__ att_dst1,
                                                uchar* __restrict__ Hout,
                                                float* __restrict__ asrc,
                                                float* __restrict__ adst) {
    int bmi = blockIdx.x;
    int head = threadIdx.x >> 6;
    int bm = bmi * 64;
    int l = threadIdx.x & 63;
    int l16 = l & 15, kg = l >> 4;

    const ushort* Abase = Xp + (size_t)bmi * NT * 2048 + l * 8;
    const ushort* Bbase = Wp + (size_t)head * NT * 2048 + l * 8;

    f32x4 zz = {0.f, 0.f, 0.f, 0.f};
    f32x4 acc[4][4];
    #pragma unroll
    for (int i = 0; i < 4; ++i)
        #pragma unroll
        for (int j = 0; j < 4; ++j) acc[i][j] = zz;

    f16x8 aX[4], bX[4], aY[4], bY[4];
    #pragma unroll
    for (int f = 0; f < 4; ++f) {
        aX[f] = *(const f16x8*)(Abase + f * 512);
        bX[f] = *(const f16x8*)(Bbase + f * 512);
    }

    #pragma unroll
    for (int kk = 0; kk < NT; kk += 2) {
        if (kk + 1 < NT) {
            #pragma unroll
            for (int f = 0; f < 4; ++f) {
                aY[f] = *(const f16x8*)(Abase + (kk + 1) * 2048 + f * 512);
                bY[f] = *(const f16x8*)(Bbase + (kk + 1) * 2048 + f * 512);
            }
        }
        #pragma unroll
        for (int fr = 0; fr < 4; ++fr)
            #pragma unroll
            for (int fc = 0; fc < 4; ++fc)
                acc[fr][fc] = __builtin_amdgcn_mfma_f32_16x16x32_f16(aX[fr], bX[fc], acc[fr][fc], 0, 0, 0);
        if (kk + 2 < NT) {
            #pragma unroll
            for (int f = 0; f < 4; ++f) {
                aX[f] = *(const f16x8*)(Abase + (kk + 2) * 2048 + f * 512);
                bX[f] = *(const f16x8*)(Bbase + (kk + 2) * 2048 + f * 512);
            }
        }
        if (kk + 1 < NT) {
            #pragma unroll
            for (int fr = 0; fr < 4; ++fr)
                #pragma unroll
                for (int fc = 0; fc < 4; ++fc)
                    acc[fr][fc] = __builtin_amdgcn_mfma_f32_16x16x32_f16(aY[fr], bY[fc], acc[fr][fc], 0, 0, 0);
        }
    }

    // ---- epilogue: store h1 (fp8 e4m3), fused alpha_src/alpha_dst ----
    float sv[4], dv[4];
    #pragma unroll
    for (int fc = 0; fc < 4; ++fc) {
        sv[fc] = att_src1[head * 64 + fc * 16 + l16];
        dv[fc] = att_dst1[head * 64 + fc * 16 + l16];
    }
    #pragma unroll
    for (int fr = 0; fr < 4; ++fr) {
        #pragma unroll
        for (int r = 0; r < 4; ++r) {
            int row = bm + fr * 16 + kg * 4 + r;
            bool ok = row < MM;
            float ps = 0.f, pd = 0.f;
            #pragma unroll
            for (int fc = 0; fc < 4; ++fc) {
                float val = acc[fr][fc][r];
                if (ok) {
                    int pk = __builtin_amdgcn_cvt_pk_fp8_f32(val, val, 0, false);
                    Hout[(size_t)row * HC + head * 64 + fc * 16 + l16] = (uchar)(pk & 0xff);
                }
                ps = fmaf(val, sv[fc], ps);
                pd = fmaf(val, dv[fc], pd);
            }
            #pragma unroll
            for (int o = 1; o < 16; o <<= 1) {
                ps += __shfl_xor(ps, o);
                pd += __shfl_xor(pd, o);
            }
            if (l16 == 0 && ok) {
                asrc[(size_t)row * HH + head] = ps;
                adst[(size_t)row * HH + head] = pd;
            }
        }
    }
}

// ------------- layer-1 aggregation fused with h2 = relu(out+b) @ W2 -------------
// ONE WAVE PER NODE, no LDS, no barriers. (round-11 version, verbatim — the
// shfl redistribution beats per-edge scalar loads: r15 A/B showed 56.5 vs 76.8 µs)

__global__ __launch_bounds__(256) void layer1_agg(const uchar* __restrict__ h1,
                                                  const float* __restrict__ w_csr,
                                                  const int* __restrict__ offs,
                                                  const int* __restrict__ csr_src,
                                                  const float* __restrict__ bias1,
                                                  const float* __restrict__ W2,
                                                  float* __restrict__ h2) {
    int a = blockIdx.y;
    int wid = threadIdx.x >> 6, l = threadIdx.x & 63;
    int n = blockIdx.x * 4 + wid;
    int eg = l >> 3;          // edge slot within chunk (also gather head gh)
    int gh = l >> 3;

    const int* offsA = offs + a * (NN + 1);
    int beg = offsA[n], end = offsA[n + 1];
    int deg = end - beg;
    const int* srcs = csr_src + (size_t)a * EE + beg;
    const float* wA = w_csr + ((size_t)a * EE + beg) * HH;
    const uchar* h1A = h1 + (size_t)a * NN * HC;

    float denom = 0.f;
    float acc[8] = {};

    float w_cur = (eg < deg) ? wA[l] : 0.f;          // wA[(c0+eg)*8+hd8] == wA[c0*8+l]
    int s_cur = (eg < deg) ? srcs[eg] : 0;

    for (int c0 = 0; c0 < deg; c0 += 8) {
        float w_nxt = 0.f;
        int s_nxt = 0;
        if (c0 + 8 + eg < deg) {
            w_nxt = wA[(c0 + 8) * 8 + l];
            s_nxt = srcs[c0 + 8 + eg];
        }
        #pragma unroll
        for (int j = 0; j < 8; ++j) {
            if (c0 + j < deg) {
                float wj = __shfl(w_cur, j * 8 + gh);
                int sj = __shfl(s_cur, j * 8);
                uint2 hv = *(const uint2*)(h1A + (size_t)sj * HC + (l << 3));
                f32x2 p0 = __builtin_amdgcn_cvt_pk_f32_fp8((int)hv.x, false);
                f32x2 p1 = __builtin_amdgcn_cvt_pk_f32_fp8((int)hv.x, true);
                f32x2 p2 = __builtin_amdgcn_cvt_pk_f32_fp8((int)hv.y, false);
                f32x2 p3 = __builtin_amdgcn_cvt_pk_f32_fp8((int)hv.y, true);
                acc[0] = fmaf(wj, p0[0], acc[0]);
                acc[1] = fmaf(wj, p0[1], acc[1]);
                acc[2] = fmaf(wj, p1[0], acc[2]);
                acc[3] = fmaf(wj, p1[1], acc[3]);
                acc[4] = fmaf(wj, p2[0], acc[4]);
                acc[5] = fmaf(wj, p2[1], acc[5]);
                acc[6] = fmaf(wj, p3[0], acc[6]);
                acc[7] = fmaf(wj, p3[1], acc[7]);
            }
        }
        denom += w_cur;
        w_cur = w_nxt;
        s_cur = s_nxt;
    }
    #pragma unroll
    for (int o = 8; o < 64; o <<= 1) denom += __shfl_xor(denom, o);
    float dn = __shfl(denom, gh);
    float inv = 1.f / (dn + 1e-16f);

    int cb = l * 8;
    float4 b0 = *(const float4*)(bias1 + cb);
    float4 b1 = *(const float4*)(bias1 + cb + 4);
    float4 w0 = *(const float4*)(W2 + cb);
    float4 w1 = *(const float4*)(W2 + cb + 4);
    float bz[8] = {b0.x, b0.y, b0.z, b0.w, b1.x, b1.y, b1.z, b1.w};
    float wz[8] = {w0.x, w0.y, w0.z, w0.w, w1.x, w1.y, w1.z, w1.w};
    float p = 0.f;
    #pragma unroll
    for (int k = 0; k < 8; ++k) {
        float z = fmaf(acc[k], inv, bz[k]);
        z = z > 0.f ? z : 0.f;
        p = fmaf(z, wz[k], p);
    }
    #pragma unroll
    for (int o = 1; o < 64; o <<= 1) p += __shfl_xor(p, o);
    if (l == 0) h2[(size_t)a * NN + n] = p;
}

// ---------------- layer 2 (scalar per node) -> proba partials ----------------

#define L2GRID 40

__global__ __launch_bounds__(256) void layer2_proba(const float* __restrict__ h2,
                                                    const int* __restrict__ offs,
                                                    const int* __restrict__ csr_src,
                                                    const float* __restrict__ att_src2,
                                                    const float* __restrict__ att_dst2,
                                                    const float* __restrict__ bias2,
                                                    float* __restrict__ partials) {
    int a = blockIdx.y;
    int n = blockIdx.x * 256 + threadIdx.x;
    float out2 = 0.f;
    if (n < NN) {
        const int* offsA = offs + a * (NN + 1);
        const int* srcs = csr_src + (size_t)a * EE;
        const float* h2A = h2 + (size_t)a * NN;
        float as2 = att_src2[0], ad2 = att_dst2[0];
        int beg = offsA[n], end = offsA[n + 1];
        float adn = h2A[n] * ad2;
        float denom = 0.f, accv = 0.f;
        for (int i = beg; i < end; ++i) {
            float hs = h2A[srcs[i]];
            float v = fmaf(hs, as2, adn);
            v = v > 0.f ? v : 0.2f * v;
            float w = __expf(v);
            denom += w;
            accv = fmaf(w, hs, accv);
        }
        out2 = accv / (denom + 1e-16f) + bias2[0];
    }
    __shared__ float red[256];
    red[threadIdx.x] = out2;
    __syncthreads();
    for (int s = 128; s > 0; s >>= 1) {
        if (threadIdx.x < s) red[threadIdx.x] += red[threadIdx.x + s];
        __syncthreads();
    }
    if (threadIdx.x == 0) partials[a * L2GRID + blockIdx.x] = red[0];
}

// finalize + sel in ONE kernel: every block redundantly computes pv/argmax
// from the 200 partials (cheap, L2-hot); block 0 writes proba, all write sel.

__global__ __launch_bounds__(256) void finalize_all(const float* __restrict__ partials,
                                                    const int* __restrict__ cnt,
                                                    float* __restrict__ out) {
    int tid = threadIdx.x;
    __shared__ float red[256];
    __shared__ int sbest;
    red[tid] = (tid < AA * L2GRID) ? partials[tid] : 0.f;
    __syncthreads();
    if (tid == 0) {
        float pv[AA];
        int b = 0;
        for (int a = 0; a < AA; ++a) {
            float s = 0.f;
            for (int i = 0; i < L2GRID; ++i) s += red[a * L2GRID + i];
            pv[a] = s / (float)NN;
            if (blockIdx.x == 0) out[a] = pv[a];
            if (pv[a] > pv[b]) b = a;
        }
        sbest = b;
    }
    __syncthreads();
    int n = blockIdx.x * 256 + tid;
    if (n < NN) out[AA + n] = (cnt[sbest * NN + n] > 0) ? 1.0f : 0.0f;
}

// ---------------- launch ----------------

extern "C" void kernel_launch(void* const* d_in, const int* in_sizes, int n_in,
                              void* d_out, int out_size, void* d_ws, size_t ws_size,
                              hipStream_t stream) {
    const float* x        = (const float*)d_in[0];
    const int*   ei       = (const int*)d_in[1];
    const float* W1       = (const float*)d_in[2];
    const float* att_src1 = (const float*)d_in[3];
    const float* att_dst1 = (const float*)d_in[4];
    const float* bias1    = (const float*)d_in[5];
    const float* W2       = (const float*)d_in[6];
    const float* att_src2 = (const float*)d_in[7];
    const float* att_dst2 = (const float*)d_in[8];
    const float* bias2    = (const float*)d_in[9];
    float* out = (float*)d_out;

    char* ws = (char*)d_ws;
    size_t off = 0;
    auto alloc = [&](size_t bytes) {
        size_t cur = off;
        off += (bytes + 255) & ~(size_t)255;
        return cur;
    };
    uchar*  h1      = (uchar*)(ws + alloc(sizeof(uchar) * (size_t)MM * HC));           // 25.6 MB
    ushort* xp      = (ushort*)(ws + alloc(sizeof(ushort) * (size_t)NBM * NT * 2048)); // 32 MB
    float*  asrc    = (float*)(ws + alloc(sizeof(float) * (size_t)MM * HH));
    float*  adst    = (float*)(ws + alloc(sizeof(float) * (size_t)MM * HH));
    float*  h2      = (float*)(ws + alloc(sizeof(float) * (size_t)MM));
    int*    cnt     = (int*)(ws + alloc(sizeof(int) * (size_t)AA * NN));
    int*    offs    = (int*)(ws + alloc(sizeof(int) * (size_t)AA * (NN + 1)));
    int*    cursor  = (int*)(ws + alloc(sizeof(int) * (size_t)AA * (NN + 1)));
    int*    bsum    = (int*)(ws + alloc(sizeof(int) * (size_t)AA * SCB));
    int*    boff    = (int*)(ws + alloc(sizeof(int) * (size_t)AA * SCB));
    int*    csr_src = (int*)(ws + alloc(sizeof(int) * (size_t)AA * EE));
    float*  w_csr   = (float*)(ws + alloc(sizeof(float) * (size_t)AA * EE * HH));      // 20.5 MB
    float*  partials= (float*)(ws + alloc(sizeof(float) * AA * L2GRID));
    ushort* wp      = (ushort*)(ws + alloc(sizeof(ushort) * (size_t)HH * NT * 2048)); // 320 KB
    (void)ws_size; (void)in_sizes; (void)n_in; (void)out_size;

    // pack x + W in one kernel
    pack_all<<<dim3((PXN + HH * NT * 256 + 255) / 256), dim3(256), 0, stream>>>(
        x, W1, xp, wp);

    hipMemsetAsync(cnt, 0, sizeof(int) * (size_t)AA * NN, stream);
    count_edges<<<dim3(EE / 256, AA), dim3(256), 0, stream>>>(ei, cnt);
    scan_bsum<<<dim3(SCB, AA), dim3(256), 0, stream>>>(cnt, bsum);
    scan_bscan<<<dim3(AA), dim3(64), 0, stream>>>(bsum, boff, offs);
    scan_final<<<dim3(SCB, AA), dim3(256), 0, stream>>>(cnt, boff, offs, cursor);

    // gemm before scatter: scatter_fused consumes asrc/adst for edge weights
    gemm_f16<<<dim3(NBM), dim3(512), 0, stream>>>(
        xp, wp, att_src1, att_dst1, h1, asrc, adst);

    scatter_fused<<<dim3(EE / 256, AA), dim3(256), 0, stream>>>(ei, cursor, csr_src,
                                                                asrc, adst, w_csr);

    layer1_agg<<<dim3(NN / 4, AA), dim3(256), 0, stream>>>(h1, w_csr, offs, csr_src,
                                                           bias1, W2, h2);

    layer2_proba<<<dim3(L2GRID, AA), dim3(256), 0, stream>>>(h2, offs, csr_src,
                                                             att_src2, att_dst2, bias2,
                                                             partials);

    finalize_all<<<dim3(L2GRID), dim3(256), 0, stream>>>(partials, cnt, out);
}

// Round 19
// 201.701 us; speedup vs baseline: 1.4245x; 1.0301x over previous
//
#include <hip/hip_runtime.h>
#include <hip/hip_bf16.h>
#include <math.h>

#define NN 10000
#define EE 128000
#define AA 5
#define DD 300
#define HH 8
#define CC 64
#define HC 512
#define MM (AA*NN)   // 50000 rows total
#define KP 320       // K padded to multiple of 32
#define NT (KP / 32) // 10 K-steps
#define NBM ((MM + 63) / 64)   // 782 row-tiles
#define SCB 40       // scan: blocks per answer
#define SCN 250      // scan: nodes per block  (SCB*SCN == NN)
#define PXN (NBM * NT * 4 * 64)   // pack_x element count

typedef __attribute__((ext_vector_type(8))) _Float16 f16x8;
typedef __attribute__((ext_vector_type(4))) float f32x4;
typedef __attribute__((ext_vector_type(2))) float f32x2;
typedef unsigned short ushort;
typedef unsigned char uchar;

__device__ __forceinline__ float bf2f(ushort h) {
    return __uint_as_float(((unsigned)h) << 16);
}
__device__ __forceinline__ float leaky_exp(float v) {
    v = v > 0.f ? v : 0.2f * v;
    return __expf(v);
}

// ---------------- CSR build ----------------

__global__ void count_edges(const int* __restrict__ ei, int* __restrict__ cnt) {
    int a = blockIdx.y;
    int e = blockIdx.x * 256 + threadIdx.x;
    if (e < EE) {
        int dst = ei[(size_t)a * 2 * EE + EE + e];
        atomicAdd(&cnt[a * NN + dst], 1);
    }
}

// --- hierarchical exclusive scan of cnt -> offs, cursor (3 small kernels) ---

__global__ __launch_bounds__(256) void scan_bsum(const int* __restrict__ cnt,
                                                 int* __restrict__ bsum) {
    int a = blockIdx.y, b = blockIdx.x;
    int l = threadIdx.x;
    int v = (l < SCN) ? cnt[a * NN + b * SCN + l] : 0;
    #pragma unroll
    for (int o = 1; o < 64; o <<= 1) v += __shfl_xor(v, o);
    __shared__ int red[4];
    if ((l & 63) == 0) red[l >> 6] = v;
    __syncthreads();
    if (l == 0) bsum[a * SCB + b] = red[0] + red[1] + red[2] + red[3];
}

__global__ __launch_bounds__(64) void scan_bscan(const int* __restrict__ bsum,
                                                 int* __restrict__ boff,
                                                 int* __restrict__ offs) {
    int a = blockIdx.x;
    int l = threadIdx.x;
    int v = (l < SCB) ? bsum[a * SCB + l] : 0;
    int sc = v;
    #pragma unroll
    for (int o = 1; o < 64; o <<= 1) {
        int u = __shfl_up(sc, o);
        if (l >= o) sc += u;
    }
    if (l < SCB) boff[a * SCB + l] = sc - v;
    if (l == 63) offs[a * (NN + 1) + NN] = sc;   // grand total
}

__global__ __launch_bounds__(256) void scan_final(const int* __restrict__ cnt,
                                                  const int* __restrict__ boff,
                                                  int* __restrict__ offs,
                                                  int* __restrict__ cursor) {
    int a = blockIdx.y, b = blockIdx.x;
    int l = threadIdx.x;
    int i = b * SCN + l;
    int v = (l < SCN) ? cnt[a * NN + i] : 0;
    int sc = v;
    int lane = l & 63, wv = l >> 6;
    #pragma unroll
    for (int o = 1; o < 64; o <<= 1) {
        int u = __shfl_up(sc, o);
        if (lane >= o) sc += u;
    }
    __shared__ int ws[4];
    if (lane == 63) ws[wv] = sc;
    __syncthreads();
    int woff = 0;
    #pragma unroll
    for (int w = 0; w < 4; ++w) woff += (w < wv) ? ws[w] : 0;
    if (l < SCN) {
        int o = boff[a * SCB + b] + woff + sc - v;
        offs[a * (NN + 1) + i] = o;
        cursor[a * (NN + 1) + i] = o;
    }
}

// scatter + fused edge weights (bucket order nondeterministic; fp32 reorder
// noise ~1e-6 on h2 << threshold 2e-2 and argmax margins >1.2e-4).

__global__ __launch_bounds__(256) void scatter_fused(const int* __restrict__ ei,
                                                     int* __restrict__ cursor,
                                                     int* __restrict__ csr_src,
                                                     const float* __restrict__ asrc,
                                                     const float* __restrict__ adst,
                                                     float* __restrict__ w_csr) {
    int a = blockIdx.y;
    int e = blockIdx.x * 256 + threadIdx.x;
    if (e >= EE) return;
    int src = ei[(size_t)a * 2 * EE + e];
    int dst = ei[(size_t)a * 2 * EE + EE + e];
    int pos = atomicAdd(&cursor[a * (NN + 1) + dst], 1);
    csr_src[(size_t)a * EE + pos] = src;
    const float* asrcA = asrc + (size_t)a * NN * HH;
    const float* adstA = adst + (size_t)a * NN * HH;
    float4 s0 = *(const float4*)(asrcA + (size_t)src * HH);
    float4 s1 = *(const float4*)(asrcA + (size_t)src * HH + 4);
    float4 d0 = *(const float4*)(adstA + (size_t)dst * HH);
    float4 d1 = *(const float4*)(adstA + (size_t)dst * HH + 4);
    float4 w0, w1;
    w0.x = leaky_exp(s0.x + d0.x); w0.y = leaky_exp(s0.y + d0.y);
    w0.z = leaky_exp(s0.z + d0.z); w0.w = leaky_exp(s0.w + d0.w);
    w1.x = leaky_exp(s1.x + d1.x); w1.y = leaky_exp(s1.y + d1.y);
    w1.z = leaky_exp(s1.z + d1.z); w1.w = leaky_exp(s1.w + d1.w);
    float* wp = w_csr + ((size_t)a * EE + pos) * HH;
    *(float4*)(wp) = w0;
    *(float4*)(wp + 4) = w1;
}

// ---------- pack x AND W1 into MFMA-fragment order (fp16), one kernel ----------
// Layout: P[((tile*NT + ks)*4 + frag)*64 + lane] : f16x8

__global__ __launch_bounds__(256) void pack_all(const float* __restrict__ X,
                                                const float* __restrict__ W,
                                                ushort* __restrict__ Xp,
                                                ushort* __restrict__ Wp) {
    int gid = blockIdx.x * 256 + threadIdx.x;
    if (gid < PXN) {
        int l = gid & 63;
        int fr = (gid >> 6) & 3;
        int rest = gid >> 8;
        int ks = rest % NT;
        int bmi = rest / NT;
        int row = bmi * 64 + fr * 16 + (l & 15);
        int k = ks * 32 + (l >> 4) * 8;
        f16x8 o;
        if (row < MM && k + 8 <= DD) {
            float4 v0 = *(const float4*)(X + (size_t)row * DD + k);
            float4 v1 = *(const float4*)(X + (size_t)row * DD + k + 4);
            o[0] = (_Float16)v0.x; o[1] = (_Float16)v0.y;
            o[2] = (_Float16)v0.z; o[3] = (_Float16)v0.w;
            o[4] = (_Float16)v1.x; o[5] = (_Float16)v1.y;
            o[6] = (_Float16)v1.z; o[7] = (_Float16)v1.w;
        } else {
            #pragma unroll
            for (int j = 0; j < 8; ++j)
                o[j] = (row < MM && k + j < DD) ? (_Float16)X[(size_t)row * DD + k + j]
                                                : (_Float16)0.f;
        }
        *(f16x8*)(Xp + (size_t)gid * 8) = o;
    } else {
        int g2 = gid - PXN;
        if (g2 >= HH * NT * 4 * 64) return;
        int l = g2 & 63;
        int fc = (g2 >> 6) & 3;
        int rest = g2 >> 8;
        int ks = rest % NT;
        int head = rest / NT;
        int col = head * 64 + fc * 16 + (l & 15);
        int k = ks * 32 + (l >> 4) * 8;
        f16x8 o;
        #pragma unroll
        for (int j = 0; j < 8; ++j)
            o[j] = (k + j < DD) ? (_Float16)W[(size_t)(k + j) * HC + col] : (_Float16)0.f;
        *(f16x8*)(Wp + (size_t)g2 * 8) = o;
    }
}

// ---- fp16 MFMA GEMM: h1 = x @ W1, packed operands, no LDS, no barriers ----
// ONE BLOCK PER bmi, 8 waves = 8 heads.

__global__ __launch_bounds__(512) void gemm_f16(const ushort* __restrict__ Xp,
                                                const ushort* __restrict__ Wp,
                                                const float* __restrict__ att_src1,
                                                const float* __restrict__ att_dst1,
                                                uchar* __restrict__ Hout,
                                                float* __restrict__ asrc,
                                                float* __restrict__ adst) {
    int bmi = blockIdx.x;
    int head = threadIdx.x >> 6;
    int bm = bmi * 64;
    int l = threadIdx.x & 63;
    int l16 = l & 15, kg = l >> 4;

    const ushort* Abase = Xp + (size_t)bmi * NT * 2048 + l * 8;
    const ushort* Bbase = Wp + (size_t)head * NT * 2048 + l * 8;

    f32x4 zz = {0.f, 0.f, 0.f, 0.f};
    f32x4 acc[4][4];
    #pragma unroll
    for (int i = 0; i < 4; ++i)
        #pragma unroll
        for (int j = 0; j < 4; ++j) acc[i][j] = zz;

    f16x8 aX[4], bX[4], aY[4], bY[4];
    #pragma unroll
    for (int f = 0; f < 4; ++f) {
        aX[f] = *(const f16x8*)(Abase + f * 512);
        bX[f] = *(const f16x8*)(Bbase + f * 512);
    }

    #pragma unroll
    for (int kk = 0; kk < NT; kk += 2) {
        if (kk + 1 < NT) {
            #pragma unroll
            for (int f = 0; f < 4; ++f) {
                aY[f] = *(const f16x8*)(Abase + (kk + 1) * 2048 + f * 512);
                bY[f] = *(const f16x8*)(Bbase + (kk + 1) * 2048 + f * 512);
            }
        }
        #pragma unroll
        for (int fr = 0; fr < 4; ++fr)
            #pragma unroll
            for (int fc = 0; fc < 4; ++fc)
                acc[fr][fc] = __builtin_amdgcn_mfma_f32_16x16x32_f16(aX[fr], bX[fc], acc[fr][fc], 0, 0, 0);
        if (kk + 2 < NT) {
            #pragma unroll
            for (int f = 0; f < 4; ++f) {
                aX[f] = *(const f16x8*)(Abase + (kk + 2) * 2048 + f * 512);
                bX[f] = *(const f16x8*)(Bbase + (kk + 2) * 2048 + f * 512);
            }
        }
        if (kk + 1 < NT) {
            #pragma unroll
            for (int fr = 0; fr < 4; ++fr)
                #pragma unroll
                for (int fc = 0; fc < 4; ++fc)
                    acc[fr][fc] = __builtin_amdgcn_mfma_f32_16x16x32_f16(aY[fr], bY[fc], acc[fr][fc], 0, 0, 0);
        }
    }

    // ---- epilogue: store h1 (fp8 e4m3), fused alpha_src/alpha_dst ----
    float sv[4], dv[4];
    #pragma unroll
    for (int fc = 0; fc < 4; ++fc) {
        sv[fc] = att_src1[head * 64 + fc * 16 + l16];
        dv[fc] = att_dst1[head * 64 + fc * 16 + l16];
    }
    #pragma unroll
    for (int fr = 0; fr < 4; ++fr) {
        #pragma unroll
        for (int r = 0; r < 4; ++r) {
            int row = bm + fr * 16 + kg * 4 + r;
            bool ok = row < MM;
            float ps = 0.f, pd = 0.f;
            #pragma unroll
            for (int fc = 0; fc < 4; ++fc) {
                float val = acc[fr][fc][r];
                if (ok) {
                    int pk = __builtin_amdgcn_cvt_pk_fp8_f32(val, val, 0, false);
                    Hout[(size_t)row * HC + head * 64 + fc * 16 + l16] = (uchar)(pk & 0xff);
                }
                ps = fmaf(val, sv[fc], ps);
                pd = fmaf(val, dv[fc], pd);
            }
            #pragma unroll
            for (int o = 1; o < 16; o <<= 1) {
                ps += __shfl_xor(ps, o);
                pd += __shfl_xor(pd, o);
            }
            if (l16 == 0 && ok) {
                asrc[(size_t)row * HH + head] = ps;
                adst[(size_t)row * HH + head] = pd;
            }
        }
    }
}

// ------------- layer-1 aggregation fused with h2 = relu(out+b) @ W2 -------------
// ONE WAVE PER NODE. 16B/lane gather: lanes 0-31 cover edge j's full 512B row,
// lanes 32-63 edge j+1 -> one dwordx4 wave-load feeds TWO edges (half the loads
// and half the wj/sj shuffles of the 8B/lane version). acc[16]/lane; halves
// folded once at the end. Denominator unchanged (coalesced chunk loads).

__global__ __launch_bounds__(256) void layer1_agg(const uchar* __restrict__ h1,
                                                  const float* __restrict__ w_csr,
                                                  const int* __restrict__ offs,
                                                  const int* __restrict__ csr_src,
                                                  const float* __restrict__ bias1,
                                                  const float* __restrict__ W2,
                                                  float* __restrict__ h2) {
    int a = blockIdx.y;
    int wid = threadIdx.x >> 6, l = threadIdx.x & 63;
    int n = blockIdx.x * 4 + wid;
    int eg = l >> 3;              // denom: edge slot within chunk
    int half = l >> 5;            // gather: which edge of the pair
    int l31 = l & 31;             // gather: 16B slot within row
    int gh2 = l31 >> 2;           // gather: head of this lane's 16 channels

    const int* offsA = offs + a * (NN + 1);
    int beg = offsA[n], end = offsA[n + 1];
    int deg = end - beg;
    const int* srcs = csr_src + (size_t)a * EE + beg;
    const float* wA = w_csr + ((size_t)a * EE + beg) * HH;
    const uchar* h1A = h1 + (size_t)a * NN * HC;

    float denom = 0.f;
    float acc[16] = {};

    float w_cur = (eg < deg) ? wA[l] : 0.f;          // (edge c0+eg, head l&7)
    int s_cur = (eg < deg) ? srcs[eg] : 0;

    for (int c0 = 0; c0 < deg; c0 += 8) {
        float w_nxt = 0.f;
        int s_nxt = 0;
        if (c0 + 8 + eg < deg) {
            w_nxt = wA[(c0 + 8) * 8 + l];
            s_nxt = srcs[c0 + 8 + eg];
        }
        #pragma unroll
        for (int j = 0; j < 8; j += 2) {
            if (c0 + j < deg) {
                int ep = j + half;                      // this half's edge slot
                float wj = __shfl(w_cur, ep * 8 + gh2); // 0 for pad edges
                int sj = __shfl(s_cur, ep * 8);
                uint4 hv = *(const uint4*)(h1A + (size_t)sj * HC + (l31 << 4));
                f32x2 p0 = __builtin_amdgcn_cvt_pk_f32_fp8((int)hv.x, false);
                f32x2 p1 = __builtin_amdgcn_cvt_pk_f32_fp8((int)hv.x, true);
                f32x2 p2 = __builtin_amdgcn_cvt_pk_f32_fp8((int)hv.y, false);
                f32x2 p3 = __builtin_amdgcn_cvt_pk_f32_fp8((int)hv.y, true);
                f32x2 p4 = __builtin_amdgcn_cvt_pk_f32_fp8((int)hv.z, false);
                f32x2 p5 = __builtin_amdgcn_cvt_pk_f32_fp8((int)hv.z, true);
                f32x2 p6 = __builtin_amdgcn_cvt_pk_f32_fp8((int)hv.w, false);
                f32x2 p7 = __builtin_amdgcn_cvt_pk_f32_fp8((int)hv.w, true);
                acc[0]  = fmaf(wj, p0[0], acc[0]);
                acc[1]  = fmaf(wj, p0[1], acc[1]);
                acc[2]  = fmaf(wj, p1[0], acc[2]);
                acc[3]  = fmaf(wj, p1[1], acc[3]);
                acc[4]  = fmaf(wj, p2[0], acc[4]);
                acc[5]  = fmaf(wj, p2[1], acc[5]);
                acc[6]  = fmaf(wj, p3[0], acc[6]);
                acc[7]  = fmaf(wj, p3[1], acc[7]);
                acc[8]  = fmaf(wj, p4[0], acc[8]);
                acc[9]  = fmaf(wj, p4[1], acc[9]);
                acc[10] = fmaf(wj, p5[0], acc[10]);
                acc[11] = fmaf(wj, p5[1], acc[11]);
                acc[12] = fmaf(wj, p6[0], acc[12]);
                acc[13] = fmaf(wj, p6[1], acc[13]);
                acc[14] = fmaf(wj, p7[0], acc[14]);
                acc[15] = fmaf(wj, p7[1], acc[15]);
            }
        }
        denom += w_cur;
        w_cur = w_nxt;
        s_cur = s_nxt;
    }
    // fold the two edge-halves: lanes l and l^32 hold the same 16 channels
    #pragma unroll
    for (int k = 0; k < 16; ++k) acc[k] += __shfl_xor(acc[k], 32);
    // denom: lane l holds partial for head (l&7); fold edge-slots
    #pragma unroll
    for (int o = 8; o < 64; o <<= 1) denom += __shfl_xor(denom, o);
    float dn = __shfl(denom, gh2);       // lane gh2 (<8) holds denom[head gh2]
    float inv = 1.f / (dn + 1e-16f);

    int cb = l31 * 16;                   // 16 channels per lane
    float p = 0.f;
    #pragma unroll
    for (int q = 0; q < 4; ++q) {
        float4 bv = *(const float4*)(bias1 + cb + q * 4);
        float4 wv = *(const float4*)(W2 + cb + q * 4);
        float z0 = fmaf(acc[q * 4 + 0], inv, bv.x); z0 = z0 > 0.f ? z0 : 0.f;
        float z1 = fmaf(acc[q * 4 + 1], inv, bv.y); z1 = z1 > 0.f ? z1 : 0.f;
        float z2 = fmaf(acc[q * 4 + 2], inv, bv.z); z2 = z2 > 0.f ? z2 : 0.f;
        float z3 = fmaf(acc[q * 4 + 3], inv, bv.w); z3 = z3 > 0.f ? z3 : 0.f;
        p = fmaf(z0, wv.x, p);
        p = fmaf(z1, wv.y, p);
        p = fmaf(z2, wv.z, p);
        p = fmaf(z3, wv.w, p);
    }
    // both halves hold identical sums; reduce within the 32-lane group
    #pragma unroll
    for (int o = 1; o < 32; o <<= 1) p += __shfl_xor(p, o);
    if (l == 0) h2[(size_t)a * NN + n] = p;
}

// ---------------- layer 2 (scalar per node) -> proba partials ----------------

#define L2GRID 40

__global__ __launch_bounds__(256) void layer2_proba(const float* __restrict__ h2,
                                                    const int* __restrict__ offs,
                                                    const int* __restrict__ csr_src,
                                                    const float* __restrict__ att_src2,
                                                    const float* __restrict__ att_dst2,
                                                    const float* __restrict__ bias2,
                                                    float* __restrict__ partials) {
    int a = blockIdx.y;
    int n = blockIdx.x * 256 + threadIdx.x;
    float out2 = 0.f;
    if (n < NN) {
        const int* offsA = offs + a * (NN + 1);
        const int* srcs = csr_src + (size_t)a * EE;
        const float* h2A = h2 + (size_t)a * NN;
        float as2 = att_src2[0], ad2 = att_dst2[0];
        int beg = offsA[n], end = offsA[n + 1];
        float adn = h2A[n] * ad2;
        float denom = 0.f, accv = 0.f;
        for (int i = beg; i < end; ++i) {
            float hs = h2A[srcs[i]];
            float v = fmaf(hs, as2, adn);
            v = v > 0.f ? v : 0.2f * v;
            float w = __expf(v);
            denom += w;
            accv = fmaf(w, hs, accv);
        }
        out2 = accv / (denom + 1e-16f) + bias2[0];
    }
    __shared__ float red[256];
    red[threadIdx.x] = out2;
    __syncthreads();
    for (int s = 128; s > 0; s >>= 1) {
        if (threadIdx.x < s) red[threadIdx.x] += red[threadIdx.x + s];
        __syncthreads();
    }
    if (threadIdx.x == 0) partials[a * L2GRID + blockIdx.x] = red[0];
}

// finalize + sel in ONE kernel.

__global__ __launch_bounds__(256) void finalize_all(const float* __restrict__ partials,
                                                    const int* __restrict__ cnt,
                                                    float* __restrict__ out) {
    int tid = threadIdx.x;
    __shared__ float red[256];
    __shared__ int sbest;
    red[tid] = (tid < AA * L2GRID) ? partials[tid] : 0.f;
    __syncthreads();
    if (tid == 0) {
        float pv[AA];
        int b = 0;
        for (int a = 0; a < AA; ++a) {
            float s = 0.f;
            for (int i = 0; i < L2GRID; ++i) s += red[a * L2GRID + i];
            pv[a] = s / (float)NN;
            if (blockIdx.x == 0) out[a] = pv[a];
            if (pv[a] > pv[b]) b = a;
        }
        sbest = b;
    }
    __syncthreads();
    int n = blockIdx.x * 256 + tid;
    if (n < NN) out[AA + n] = (cnt[sbest * NN + n] > 0) ? 1.0f : 0.0f;
}

// ---------------- launch ----------------

extern "C" void kernel_launch(void* const* d_in, const int* in_sizes, int n_in,
                              void* d_out, int out_size, void* d_ws, size_t ws_size,
                              hipStream_t stream) {
    const float* x        = (const float*)d_in[0];
    const int*   ei       = (const int*)d_in[1];
    const float* W1       = (const float*)d_in[2];
    const float* att_src1 = (const float*)d_in[3];
    const float* att_dst1 = (const float*)d_in[4];
    const float* bias1    = (const float*)d_in[5];
    const float* W2       = (const float*)d_in[6];
    const float* att_src2 = (const float*)d_in[7];
    const float* att_dst2 = (const float*)d_in[8];
    const float* bias2    = (const float*)d_in[9];
    float* out = (float*)d_out;

    char* ws = (char*)d_ws;
    size_t off = 0;
    auto alloc = [&](size_t bytes) {
        size_t cur = off;
        off += (bytes + 255) & ~(size_t)255;
        return cur;
    };
    uchar*  h1      = (uchar*)(ws + alloc(sizeof(uchar) * (size_t)MM * HC));           // 25.6 MB
    ushort* xp      = (ushort*)(ws + alloc(sizeof(ushort) * (size_t)NBM * NT * 2048)); // 32 MB
    float*  asrc    = (float*)(ws + alloc(sizeof(float) * (size_t)MM * HH));
    float*  adst    = (float*)(ws + alloc(sizeof(float) * (size_t)MM * HH));
    float*  h2      = (float*)(ws + alloc(sizeof(float) * (size_t)MM));
    int*    cnt     = (int*)(ws + alloc(sizeof(int) * (size_t)AA * NN));
    int*    offs    = (int*)(ws + alloc(sizeof(int) * (size_t)AA * (NN + 1)));
    int*    cursor  = (int*)(ws + alloc(sizeof(int) * (size_t)AA * (NN + 1)));
    int*    bsum    = (int*)(ws + alloc(sizeof(int) * (size_t)AA * SCB));
    int*    boff    = (int*)(ws + alloc(sizeof(int) * (size_t)AA * SCB));
    int*    csr_src = (int*)(ws + alloc(sizeof(int) * (size_t)AA * EE));
    float*  w_csr   = (float*)(ws + alloc(sizeof(float) * (size_t)AA * EE * HH));      // 20.5 MB
    float*  partials= (float*)(ws + alloc(sizeof(float) * AA * L2GRID));
    ushort* wp      = (ushort*)(ws + alloc(sizeof(ushort) * (size_t)HH * NT * 2048)); // 320 KB
    (void)ws_size; (void)in_sizes; (void)n_in; (void)out_size;

    pack_all<<<dim3((PXN + HH * NT * 256 + 255) / 256), dim3(256), 0, stream>>>(
        x, W1, xp, wp);

    hipMemsetAsync(cnt, 0, sizeof(int) * (size_t)AA * NN, stream);
    count_edges<<<dim3(EE / 256, AA), dim3(256), 0, stream>>>(ei, cnt);
    scan_bsum<<<dim3(SCB, AA), dim3(256), 0, stream>>>(cnt, bsum);
    scan_bscan<<<dim3(AA), dim3(64), 0, stream>>>(bsum, boff, offs);
    scan_final<<<dim3(SCB, AA), dim3(256), 0, stream>>>(cnt, boff, offs, cursor);

    gemm_f16<<<dim3(NBM), dim3(512), 0, stream>>>(
        xp, wp, att_src1, att_dst1, h1, asrc, adst);

    scatter_fused<<<dim3(EE / 256, AA), dim3(256), 0, stream>>>(ei, cursor, csr_src,
                                                                asrc, adst, w_csr);

    layer1_agg<<<dim3(NN / 4, AA), dim3(256), 0, stream>>>(h1, w_csr, offs, csr_src,
                                                           bias1, W2, h2);

    layer2_proba<<<dim3(L2GRID, AA), dim3(256), 0, stream>>>(h2, offs, csr_src,
                                                             att_src2, att_dst2, bias2,
                                                             partials);

    finalize_all<<<dim3(L2GRID), dim3(256), 0, stream>>>(partials, cnt, out);
}